// Round 13
// baseline (2181.662 us; speedup 1.0000x reference)
//
#include <hip/hip_runtime.h>
#include <hip/hip_bf16.h>

#define N_NODES 131072
#define N_EDGES 524288
#define F_IN 16
#define DIM 64
#define DNN 16
#define BK 4
#define NG 8192
#define N_ITERS 8   // NL1*NL2

typedef __bf16 bf16x8 __attribute__((ext_vector_type(8)));
typedef float f32x4 __attribute__((ext_vector_type(4)));

#define FMA4(A_, S_, W_) { (A_).x = fmaf((S_), (W_).x, (A_).x); (A_).y = fmaf((S_), (W_).y, (A_).y); \
                           (A_).z = fmaf((S_), (W_).z, (A_).z); (A_).w = fmaf((S_), (W_).w, (A_).w); }

// ---------------- degree (int) ----------------
__global__ __launch_bounds__(256) void k_degree(const int* __restrict__ ei, int* __restrict__ cnt) {
    int e = blockIdx.x * 256 + threadIdx.x;
    atomicAdd(&cnt[ei[N_EDGES + e]], 1);
}

__global__ __launch_bounds__(256) void k_invcnt(const int* __restrict__ cnt, float* __restrict__ inv) {
    int i = blockIdx.x * 256 + threadIdx.x;
    inv[i] = 1.0f / (float)max(cnt[i], 1);
}

// ---------------- CSR scan ----------------
__global__ __launch_bounds__(256) void k_scanA(const int* __restrict__ cnt, int* __restrict__ excl,
                                               int* __restrict__ bsum) {
    __shared__ int a[256], b[256];
    int t = threadIdx.x, gid = blockIdx.x * 256 + t;
    int c = cnt[gid];
    a[t] = c; __syncthreads();
    int *s = a, *d = b;
#pragma unroll
    for (int off = 1; off < 256; off <<= 1) {
        d[t] = s[t] + (t >= off ? s[t - off] : 0);
        __syncthreads();
        int* tmp = s; s = d; d = tmp;
    }
    excl[gid] = s[t] - c;
    if (t == 255) bsum[blockIdx.x] = s[255];
}

__global__ __launch_bounds__(256) void k_scanB(const int* __restrict__ bsum, int* __restrict__ boff) {
    __shared__ int a[512], b[512];
    int t = threadIdx.x;
    a[t] = bsum[t]; a[t + 256] = bsum[t + 256];
    __syncthreads();
    int *s = a, *d = b;
#pragma unroll
    for (int off = 1; off < 512; off <<= 1) {
        d[t] = s[t] + (t >= off ? s[t - off] : 0);
        int i2 = t + 256;
        d[i2] = s[i2] + (i2 >= off ? s[i2 - off] : 0);
        __syncthreads();
        int* tmp = s; s = d; d = tmp;
    }
    boff[t] = t ? s[t - 1] : 0;
    boff[t + 256] = s[t + 255];
}

__global__ __launch_bounds__(256) void k_scanC(const int* __restrict__ excl, const int* __restrict__ boff,
                                               int* __restrict__ row_ptr, int* __restrict__ cursor) {
    int gid = blockIdx.x * 256 + threadIdx.x;
    int v = excl[gid] + boff[gid >> 8];
    row_ptr[gid] = v;
    cursor[gid] = v;
    if (gid == 0) row_ptr[N_NODES] = N_EDGES;
}

// csr_src packs src (bits 0..19) | dst_local (bits 20..25)
__global__ __launch_bounds__(256) void k_scatter(const int* __restrict__ ei, const float* __restrict__ ea,
                                                 int* __restrict__ cursor, int* __restrict__ csr_src,
                                                 float4* __restrict__ csr_ea) {
    int e = blockIdx.x * 256 + threadIdx.x;
    int dst = ei[N_EDGES + e];
    int pos = atomicAdd(&cursor[dst], 1);
    csr_src[pos] = ei[e] | ((dst & 63) << 20);
    csr_ea[pos] = ((const float4*)ea)[e];
}

// ---------------- prep: bf16 B-fragment weight tiles ----------------
// Wb: gates tiles. B2b: o2 tiles K=96 (rows 0..15 root_w, 16..31 nn1b, 32..95 nn1w).
#define WB_SZ (4 * 40 * 512)
__global__ __launch_bounds__(256) void k_prep(const float* __restrict__ wih, const float* __restrict__ whh,
                                              const float* __restrict__ rw, const float* __restrict__ w1,
                                              const float* __restrict__ bih, const float* __restrict__ bhh,
                                              const float* __restrict__ nn1w, const float* __restrict__ nn1b,
                                              __bf16* __restrict__ Wb, __bf16* __restrict__ B2b,
                                              __bf16* __restrict__ w1b) {
    int idx = blockIdx.x * 256 + threadIdx.x;
    if (idx < WB_SZ) {
        int j = idx / 20480, r = idx % 20480;
        int t = r >> 9, e = r & 511;
        int jj = e & 7, c16 = (e >> 3) & 15, kq = e >> 7;
        int ct, kk; bool nih = false;
        if (t < 36) { ct = t / 3; kk = t % 3; } else { ct = 8 + (t - 36); kk = 0; nih = true; }
        int k = kk * 32 + kq * 8 + jj;
        int c = ct * 16 + c16;
        bool ngate = ct >= 8;
        float v = 0.f;
        if (nih) {
            if (k < 16) v = wih[((size_t)j * 192 + c) * 16 + k];
        } else {
            if (k < 16) v = ngate ? 0.f : wih[((size_t)j * 192 + c) * 16 + k];
            else if (k < 80) v = whh[((size_t)j * 192 + c) * 64 + (k - 16)];
            else if (k == 80) v = ngate ? bhh[j * 192 + c] : (bih[j * 192 + c] + bhh[j * 192 + c]);
        }
        Wb[idx] = (__bf16)v;
    } else if (idx < WB_SZ + 1536) {
        int e = idx - WB_SZ;
        int t = e >> 9, ee = e & 511;
        int jj = ee & 7, c16 = (ee >> 3) & 15, kq = ee >> 7;
        int krow = t * 32 + kq * 8 + jj;
        float v;
        if (krow < 16) v = rw[krow * 16 + c16];
        else {
            int i = (krow - 16) >> 4, kk = (krow - 16) & 15;
            v = (i == 0) ? nn1b[kk * 16 + c16] : nn1w[(i - 1) * 256 + kk * 16 + c16];
        }
        B2b[e] = (__bf16)v;
    } else if (idx < WB_SZ + 1536 + 1024) {
        int e = idx - (WB_SZ + 1536);
        int t2 = e >> 9, ee = e & 511;
        int jj = ee & 7, c16 = (ee >> 3) & 15, kq = ee >> 7;
        int k = t2 * 32 + kq * 8 + jj;
        w1b[e] = (__bf16)w1[k * 16 + c16];
    }
}

// ---------------- init: h = relu(x @ lin0_w + lin0_b) ----------------
__global__ __launch_bounds__(256) void k_init(const float* __restrict__ x, const float* __restrict__ w,
                                              const float* __restrict__ b, float* __restrict__ h) {
    __shared__ float s_w[F_IN * DIM];
    int tid = threadIdx.x;
    for (int i = tid; i < F_IN * DIM; i += 256) s_w[i] = w[i];
    int node = blockIdx.x * 16 + (tid >> 4);
    int c4 = tid & 15;
    const float4* xp = (const float4*)(x + (size_t)node * F_IN);
    float4 x0 = xp[0], x1 = xp[1], x2 = xp[2], x3 = xp[3];
    float xa[16] = {x0.x, x0.y, x0.z, x0.w, x1.x, x1.y, x1.z, x1.w,
                    x2.x, x2.y, x2.z, x2.w, x3.x, x3.y, x3.z, x3.w};
    __syncthreads();
    float4 acc = ((const float4*)b)[c4];
    const float4* w4 = (const float4*)s_w;
#pragma unroll
    for (int k = 0; k < 16; ++k) {
        float4 wv = w4[k * 16 + c4];
        FMA4(acc, xa[k], wv);
    }
    acc.x = fmaxf(acc.x, 0.f); acc.y = fmaxf(acc.y, 0.f);
    acc.z = fmaxf(acc.z, 0.f); acc.w = fmaxf(acc.w, 0.f);
    *(float4*)(h + (size_t)node * DIM + c4 * 4) = acc;
}

// ---------------- out1 = h @ lin1_w + lin1_b (once, pre-loop) ----------------
__global__ __launch_bounds__(256) void k_lin1(const float* __restrict__ h, const float* __restrict__ w,
                                              const float* __restrict__ b, float* __restrict__ out1) {
    __shared__ float s_h[64 * 68];
    int tid = threadIdx.x;
    int nb = blockIdx.x * 64;
    const float4* hp = (const float4*)(h + (size_t)nb * 64);
    for (int i = tid; i < 64 * 16; i += 256) {
        int n = i >> 4, q4 = i & 15;
        float4 v = hp[i];
        *(float4*)&s_h[n * 68 + q4 * 4] = v;
    }
    int ct = tid & 15;
    float wcol[64];
#pragma unroll
    for (int q = 0; q < 64; ++q) wcol[q] = w[q * 16 + ct];
    float bias = b[ct];
    __syncthreads();
    int ng = tid >> 4;
#pragma unroll
    for (int rep = 0; rep < 4; ++rep) {
        int nl = ng + 16 * rep;
        float acc = bias;
#pragma unroll
        for (int q4 = 0; q4 < 16; ++q4) {
            float4 hv = *(const float4*)&s_h[nl * 68 + q4 * 4];
            acc = fmaf(hv.x, wcol[4 * q4 + 0], acc);
            acc = fmaf(hv.y, wcol[4 * q4 + 1], acc);
            acc = fmaf(hv.z, wcol[4 * q4 + 2], acc);
            acc = fmaf(hv.w, wcol[4 * q4 + 3], acc);
        }
        out1[(size_t)(nb + nl) * 16 + ct] = acc;
    }
}

// ---------------- node v7: block-parallel edge gather (LDS f32 atomics) + MFMA GRU ----------------
// Block owns 64 contiguous dst nodes -> ONE contiguous CSR edge range (~256 edges).
// Gather: 16 lanes/edge, iterations independent (ds_add_f32 has no return dep);
// csr reads coalesced; out1[src] = one 64B line per edge. s_S[64][80] f32 accum.
// Then S*inv -> bf16 X2 = [out1|S], o2 = X2@B2 (K=96, 3 MFMAs), gates GEMM, GRU, lin1.
// LDS 79872 B -> 2 blocks/CU.
__attribute__((amdgpu_waves_per_eu(2)))
__global__ __launch_bounds__(256) void k_node(
    const float* __restrict__ out1_in, float* __restrict__ out1_out,
    const int* __restrict__ csr_src, const float4* __restrict__ csr_ea,
    const int* __restrict__ row_ptr, const float* __restrict__ inv_cnt,
    float* __restrict__ h, const __bf16* __restrict__ Wb, const __bf16* __restrict__ B2b,
    const __bf16* __restrict__ w1b, const float* __restrict__ conv_b,
    const float* __restrict__ bih, const float* __restrict__ lin1_b)
{
    __shared__ __align__(16) __bf16 s_X[64 * 104];   // 13312 B
    __shared__ __align__(16) __bf16 s_W[40 * 512];   // 40960 B
    __shared__ __align__(16) __bf16 s_B2[3 * 512];   //  3072 B
    __shared__ __align__(16) __bf16 s_w1[1024];      //  2048 B
    __shared__ __align__(16) float  s_S[64 * 80];    // 20480 B  (total 79872)
    int tid = threadIdx.x;
    int nb = blockIdx.x * 64;
    int lane = tid & 63, w = tid >> 6;
    int c16 = lane & 15, lq = lane >> 4;
    int nwb = nb + w * 16;

    // zero S accumulators
    {
        float4* z = (float4*)s_S;
#pragma unroll
        for (int i = 0; i < 5; ++i) z[tid + 256 * i] = make_float4(0.f, 0.f, 0.f, 0.f);
    }
    // prefetch own h rows (consumed in phase 3)
    float4 hreg[4];
    {
        const float4* hsrc = (const float4*)(h + (size_t)nwb * 64);
#pragma unroll
        for (int ii = 0; ii < 4; ++ii) hreg[ii] = hsrc[lane + 64 * ii];
    }
    // cooperative staging of weight tiles
    {
        const float4* src = (const float4*)Wb;
        float4* dst = (float4*)s_W;
#pragma unroll
        for (int i = 0; i < 10; ++i) dst[tid + 256 * i] = src[tid + 256 * i];
        for (int i = tid; i < 320; i += 256) {
            if (i < 192) ((float4*)s_B2)[i] = ((const float4*)B2b)[i];
            else ((float4*)s_w1)[i - 192] = ((const float4*)w1b)[i - 192];
        }
    }
    // own out1 row -> X2[.][0..15]
    {
        int n = lane >> 2, k4 = lane & 3;
        float4 v = *(const float4*)(out1_in + (size_t)(nwb + n) * 16 + k4 * 4);
        __bf16* p = &s_X[(w * 16 + n) * 104 + k4 * 4];
        p[0] = (__bf16)v.x; p[1] = (__bf16)v.y; p[2] = (__bf16)v.z; p[3] = (__bf16)v.w;
    }
    __syncthreads();

    // edge gather: 16 lanes per edge, block-parallel over the contiguous range
    {
        int g = tid >> 4, k = tid & 15;
        int E0 = row_ptr[nb], E1 = row_ptr[nb + 64];
        for (int e = E0 + g; e < E1; e += 16) {
            int v = csr_src[e];
            int src = v & 0xFFFFF, dl = v >> 20;
            float4 a = csr_ea[e];
            float xv = out1_in[(size_t)src * 16 + k];
            float* Sp = &s_S[dl * 80 + k];
            atomicAdd(Sp, xv);              // ds_add_f32, no return
            atomicAdd(Sp + 16, a.x * xv);
            atomicAdd(Sp + 32, a.y * xv);
            atomicAdd(Sp + 48, a.z * xv);
            atomicAdd(Sp + 64, a.w * xv);
        }
    }
    __syncthreads();
    // convert S*inv -> X2[.][16..95] bf16
    {
#pragma unroll
        for (int i = 0; i < 20; ++i) {
            int idx = tid + 256 * i;          // 0..5119
            int n = idx & 63, c = idx >> 6;   // c = 0..79
            float val = s_S[n * 80 + c] * inv_cnt[nb + n];
            s_X[n * 104 + 16 + c] = (__bf16)val;
        }
    }
    __syncthreads();

    // phase 2: o2 = X2 @ B2 + conv_b (K=96)
    float cb = conv_b[c16];
    f32x4 co2 = (f32x4){cb, cb, cb, cb};
#pragma unroll
    for (int kk = 0; kk < 3; ++kk) {
        bf16x8 a = *(const bf16x8*)&s_X[(w * 16 + c16) * 104 + kk * 32 + lq * 8];
        bf16x8 b = *(const bf16x8*)&s_B2[kk * 512 + lane * 8];
        co2 = __builtin_amdgcn_mfma_f32_16x16x32_bf16(a, b, co2, 0, 0, 0);
    }

    // phase 3a: rebuild X = [o2(16) | h(64) | 1 | 0..] (wave-own rows, same-wave DS order)
#pragma unroll
    for (int jr = 0; jr < 4; ++jr)
        s_X[(w * 16 + 4 * lq + jr) * 104 + c16] = (__bf16)co2[jr];
#pragma unroll
    for (int ii = 0; ii < 4; ++ii) {
        int idx = lane + 64 * ii;
        int n = idx >> 4, d4 = idx & 15;
        float4 v = hreg[ii];
        __bf16* p = &s_X[(w * 16 + n) * 104 + 16 + d4 * 4];
        p[0] = (__bf16)v.x; p[1] = (__bf16)v.y; p[2] = (__bf16)v.z; p[3] = (__bf16)v.w;
    }
    {
        int n = lane >> 2, c0 = 80 + (lane & 3) * 4;
#pragma unroll
        for (int q = 0; q < 4; ++q)
            s_X[(w * 16 + n) * 104 + c0 + q] = (c0 + q == 80) ? (__bf16)1.0f : (__bf16)0.0f;
    }

    // phase 3b: gates GEMM
    f32x4 acc[12], ani4[4];
#pragma unroll
    for (int i = 0; i < 12; ++i) acc[i] = (f32x4){0.f, 0.f, 0.f, 0.f};
#pragma unroll
    for (int i = 0; i < 4; ++i) ani4[i] = (f32x4){0.f, 0.f, 0.f, 0.f};
    bf16x8 af[3];
#pragma unroll
    for (int kk = 0; kk < 3; ++kk)
        af[kk] = *(const bf16x8*)&s_X[(w * 16 + c16) * 104 + kk * 32 + lq * 8];
#pragma unroll
    for (int ct = 0; ct < 12; ++ct) {
#pragma unroll
        for (int kk = 0; kk < 3; ++kk) {
            bf16x8 bf = *(const bf16x8*)&s_W[(ct * 3 + kk) * 512 + lane * 8];
            acc[ct] = __builtin_amdgcn_mfma_f32_16x16x32_bf16(af[kk], bf, acc[ct], 0, 0, 0);
        }
    }
#pragma unroll
    for (int ct8 = 0; ct8 < 4; ++ct8) {
        bf16x8 bf = *(const bf16x8*)&s_W[(36 + ct8) * 512 + lane * 8];
        ani4[ct8] = __builtin_amdgcn_mfma_f32_16x16x32_bf16(af[0], bf, ani4[ct8], 0, 0, 0);
    }

    // GRU epilogue
    float hn[4][4];
#pragma unroll
    for (int ct = 0; ct < 4; ++ct) {
        float bni = bih[128 + ct * 16 + c16];
#pragma unroll
        for (int jr = 0; jr < 4; ++jr) {
            int node = nb + w * 16 + 4 * lq + jr;
            float hold = h[(size_t)node * 64 + ct * 16 + c16];
            float rr = 1.f / (1.f + __expf(-acc[ct][jr]));
            float zz = 1.f / (1.f + __expf(-acc[4 + ct][jr]));
            float xx = fmaf(rr, acc[8 + ct][jr], ani4[ct][jr] + bni);
            float ax = fabsf(xx);
            float ee = __expf(-2.f * ax);
            float ncv = __builtin_copysignf((1.f - ee) / (1.f + ee), xx);
            float hv = fmaf(zz, hold - ncv, ncv);
            hn[ct][jr] = hv;
            h[(size_t)node * 64 + ct * 16 + c16] = hv;
        }
    }
#pragma unroll
    for (int ct = 0; ct < 4; ++ct)
#pragma unroll
        for (int jr = 0; jr < 4; ++jr)
            s_X[(w * 16 + 4 * lq + jr) * 104 + 16 + ct * 16 + c16] = (__bf16)hn[ct][jr];

    // fused lin1 -> out1_out
    f32x4 o1acc = (f32x4){0.f, 0.f, 0.f, 0.f};
#pragma unroll
    for (int kk = 0; kk < 2; ++kk) {
        bf16x8 a = *(const bf16x8*)&s_X[(w * 16 + c16) * 104 + 16 + kk * 32 + lq * 8];
        bf16x8 b = *(const bf16x8*)&s_w1[kk * 512 + lane * 8];
        o1acc = __builtin_amdgcn_mfma_f32_16x16x32_bf16(a, b, o1acc, 0, 0, 0);
    }
    float lb = lin1_b[c16];
#pragma unroll
    for (int jr = 0; jr < 4; ++jr) {
        int node = nb + w * 16 + 4 * lq + jr;
        out1_out[(size_t)node * 16 + c16] = o1acc[jr] + lb;
    }
}

// ---------------- final ----------------
__global__ __launch_bounds__(256) void k_final(const float* __restrict__ h, const float* __restrict__ w2,
                                               const int* __restrict__ batch, float* __restrict__ out) {
    int i = blockIdx.x * 4 + (threadIdx.x >> 6);
    int lane = threadIdx.x & 63;
    float v = h[(size_t)i * DIM + lane] * w2[lane];
#pragma unroll
    for (int off = 32; off > 0; off >>= 1) v += __shfl_down(v, off, 64);
    if (lane == 0) atomicAdd(&out[batch[i]], v);
}

extern "C" void kernel_launch(void* const* d_in, const int* in_sizes, int n_in,
                              void* d_out, int out_size, void* d_ws, size_t ws_size,
                              hipStream_t stream) {
    const float* x        = (const float*)d_in[0];
    const float* edge_attr= (const float*)d_in[1];
    const float* lin0_w   = (const float*)d_in[2];
    const float* lin0_b   = (const float*)d_in[3];
    const float* nn1_w    = (const float*)d_in[4];
    const float* nn1_b    = (const float*)d_in[5];
    const float* root_w   = (const float*)d_in[6];
    const float* conv_b   = (const float*)d_in[7];
    const float* gru_w_ih = (const float*)d_in[8];
    const float* gru_w_hh = (const float*)d_in[9];
    const float* gru_b_ih = (const float*)d_in[10];
    const float* gru_b_hh = (const float*)d_in[11];
    const float* lin1_w   = (const float*)d_in[12];
    const float* lin1_b   = (const float*)d_in[13];
    const float* lin2_w   = (const float*)d_in[14];
    const int*   ei       = (const int*)d_in[15];
    const int*   batch    = (const int*)d_in[16];
    float* out = (float*)d_out;

    char* p = (char*)d_ws;
    float*  h       = (float*)p;            p += (size_t)N_NODES * DIM * 4;
    float*  out1A   = (float*)p;            p += (size_t)N_NODES * DNN * 4;
    float*  out1B   = (float*)p;            p += (size_t)N_NODES * DNN * 4;
    float4* csr_ea  = (float4*)p;           p += (size_t)N_EDGES * 16;
    __bf16* Wb      = (__bf16*)p;           p += (size_t)WB_SZ * 2;
    __bf16* B2b     = (__bf16*)p;           p += 1536 * 2;
    __bf16* w1b     = (__bf16*)p;           p += 1024 * 2;
    int*    cnt     = (int*)p;              p += (size_t)N_NODES * 4;
    float*  inv_cnt = (float*)p;            p += (size_t)N_NODES * 4;
    int*    row_ptr = (int*)p;              p += (size_t)(N_NODES + 16) * 4;
    int*    cursor  = (int*)p;              p += (size_t)N_NODES * 4;
    int*    excl    = (int*)p;              p += (size_t)N_NODES * 4;
    int*    bsum    = (int*)p;              p += 512 * 4;
    int*    boff    = (int*)p;              p += 512 * 4;
    int*    csr_src = (int*)p;              p += (size_t)N_EDGES * 4;

    hipMemsetAsync(d_out, 0, (size_t)NG * 4, stream);
    hipMemsetAsync(cnt, 0, (size_t)N_NODES * 4, stream);
    k_prep<<<330, 256, 0, stream>>>(gru_w_ih, gru_w_hh, root_w, lin1_w, gru_b_ih, gru_b_hh,
                                    nn1_w, nn1_b, Wb, B2b, w1b);
    k_degree<<<N_EDGES / 256, 256, 0, stream>>>(ei, cnt);
    k_scanA<<<N_NODES / 256, 256, 0, stream>>>(cnt, excl, bsum);
    k_scanB<<<1, 256, 0, stream>>>(bsum, boff);
    k_scanC<<<N_NODES / 256, 256, 0, stream>>>(excl, boff, row_ptr, cursor);
    k_scatter<<<N_EDGES / 256, 256, 0, stream>>>(ei, edge_attr, cursor, csr_src, csr_ea);
    k_invcnt<<<N_NODES / 256, 256, 0, stream>>>(cnt, inv_cnt);
    k_init<<<N_NODES / 16, 256, 0, stream>>>(x, lin0_w, lin0_b, h);
    k_lin1<<<N_NODES / 64, 256, 0, stream>>>(h, lin1_w, lin1_b, out1A);

    for (int it = 0; it < N_ITERS; ++it) {
        int j = it >> 1;   // GRU index (NL2 = 2)
        const float* o_in = (it & 1) ? out1B : out1A;
        float*       o_out= (it & 1) ? out1A : out1B;
        k_node<<<N_NODES / 64, 256, 0, stream>>>(o_in, o_out, csr_src, csr_ea, row_ptr, inv_cnt,
                                                 h, Wb + (size_t)j * 40 * 512, B2b, w1b,
                                                 conv_b, gru_b_ih + (size_t)j * 192, lin1_b);
    }
    k_final<<<N_NODES / 4, 256, 0, stream>>>(h, lin2_w, batch, out);
}

// Round 14
// 668.559 us; speedup vs baseline: 3.2632x; 3.2632x over previous
//
#include <hip/hip_runtime.h>
#include <hip/hip_bf16.h>

#define N_NODES 131072
#define N_EDGES 524288
#define F_IN 16
#define DIM 64
#define DNN 16
#define BK 4
#define NG 8192
#define N_ITERS 8   // NL1*NL2

typedef __bf16 bf16x8 __attribute__((ext_vector_type(8)));
typedef float f32x4 __attribute__((ext_vector_type(4)));

#define FMA4(A_, S_, W_) { (A_).x = fmaf((S_), (W_).x, (A_).x); (A_).y = fmaf((S_), (W_).y, (A_).y); \
                           (A_).z = fmaf((S_), (W_).z, (A_).z); (A_).w = fmaf((S_), (W_).w, (A_).w); }

// ---------------- degree (int) ----------------
__global__ __launch_bounds__(256) void k_degree(const int* __restrict__ ei, int* __restrict__ cnt) {
    int e = blockIdx.x * 256 + threadIdx.x;
    atomicAdd(&cnt[ei[N_EDGES + e]], 1);
}

__global__ __launch_bounds__(256) void k_invcnt(const int* __restrict__ cnt, float* __restrict__ inv) {
    int i = blockIdx.x * 256 + threadIdx.x;
    inv[i] = 1.0f / (float)max(cnt[i], 1);
}

// ---------------- CSR scan ----------------
__global__ __launch_bounds__(256) void k_scanA(const int* __restrict__ cnt, int* __restrict__ excl,
                                               int* __restrict__ bsum) {
    __shared__ int a[256], b[256];
    int t = threadIdx.x, gid = blockIdx.x * 256 + t;
    int c = cnt[gid];
    a[t] = c; __syncthreads();
    int *s = a, *d = b;
#pragma unroll
    for (int off = 1; off < 256; off <<= 1) {
        d[t] = s[t] + (t >= off ? s[t - off] : 0);
        __syncthreads();
        int* tmp = s; s = d; d = tmp;
    }
    excl[gid] = s[t] - c;
    if (t == 255) bsum[blockIdx.x] = s[255];
}

__global__ __launch_bounds__(256) void k_scanB(const int* __restrict__ bsum, int* __restrict__ boff) {
    __shared__ int a[512], b[512];
    int t = threadIdx.x;
    a[t] = bsum[t]; a[t + 256] = bsum[t + 256];
    __syncthreads();
    int *s = a, *d = b;
#pragma unroll
    for (int off = 1; off < 512; off <<= 1) {
        d[t] = s[t] + (t >= off ? s[t - off] : 0);
        int i2 = t + 256;
        d[i2] = s[i2] + (i2 >= off ? s[i2 - off] : 0);
        __syncthreads();
        int* tmp = s; s = d; d = tmp;
    }
    boff[t] = t ? s[t - 1] : 0;
    boff[t + 256] = s[t + 255];
}

__global__ __launch_bounds__(256) void k_scanC(const int* __restrict__ excl, const int* __restrict__ boff,
                                               int* __restrict__ row_ptr, int* __restrict__ cursor) {
    int gid = blockIdx.x * 256 + threadIdx.x;
    int v = excl[gid] + boff[gid >> 8];
    row_ptr[gid] = v;
    cursor[gid] = v;
    if (gid == 0) row_ptr[N_NODES] = N_EDGES;
}

__global__ __launch_bounds__(256) void k_scatter(const int* __restrict__ ei, const float* __restrict__ ea,
                                                 int* __restrict__ cursor, int* __restrict__ csr_src,
                                                 float4* __restrict__ csr_ea) {
    int e = blockIdx.x * 256 + threadIdx.x;
    int dst = ei[N_EDGES + e];
    int pos = atomicAdd(&cursor[dst], 1);
    csr_src[pos] = ei[e];
    csr_ea[pos] = ((const float4*)ea)[e];
}

// ---------------- prep: bf16 B-fragment weight tiles ----------------
// Wb: gates tiles. B2b: o2 tiles K=96 (rows 0..15 root_w, 16..31 nn1b, 32..95 nn1w).
#define WB_SZ (4 * 40 * 512)
__global__ __launch_bounds__(256) void k_prep(const float* __restrict__ wih, const float* __restrict__ whh,
                                              const float* __restrict__ rw, const float* __restrict__ w1,
                                              const float* __restrict__ bih, const float* __restrict__ bhh,
                                              const float* __restrict__ nn1w, const float* __restrict__ nn1b,
                                              __bf16* __restrict__ Wb, __bf16* __restrict__ B2b,
                                              __bf16* __restrict__ w1b) {
    int idx = blockIdx.x * 256 + threadIdx.x;
    if (idx < WB_SZ) {
        int j = idx / 20480, r = idx % 20480;
        int t = r >> 9, e = r & 511;
        int jj = e & 7, c16 = (e >> 3) & 15, kq = e >> 7;
        int ct, kk; bool nih = false;
        if (t < 36) { ct = t / 3; kk = t % 3; } else { ct = 8 + (t - 36); kk = 0; nih = true; }
        int k = kk * 32 + kq * 8 + jj;
        int c = ct * 16 + c16;
        bool ngate = ct >= 8;
        float v = 0.f;
        if (nih) {
            if (k < 16) v = wih[((size_t)j * 192 + c) * 16 + k];
        } else {
            if (k < 16) v = ngate ? 0.f : wih[((size_t)j * 192 + c) * 16 + k];
            else if (k < 80) v = whh[((size_t)j * 192 + c) * 64 + (k - 16)];
            else if (k == 80) v = ngate ? bhh[j * 192 + c] : (bih[j * 192 + c] + bhh[j * 192 + c]);
        }
        Wb[idx] = (__bf16)v;
    } else if (idx < WB_SZ + 1536) {
        int e = idx - WB_SZ;
        int t = e >> 9, ee = e & 511;
        int jj = ee & 7, c16 = (ee >> 3) & 15, kq = ee >> 7;
        int krow = t * 32 + kq * 8 + jj;
        float v;
        if (krow < 16) v = rw[krow * 16 + c16];
        else {
            int i = (krow - 16) >> 4, kk = (krow - 16) & 15;
            v = (i == 0) ? nn1b[kk * 16 + c16] : nn1w[(i - 1) * 256 + kk * 16 + c16];
        }
        B2b[e] = (__bf16)v;
    } else if (idx < WB_SZ + 1536 + 1024) {
        int e = idx - (WB_SZ + 1536);
        int t2 = e >> 9, ee = e & 511;
        int jj = ee & 7, c16 = (ee >> 3) & 15, kq = ee >> 7;
        int k = t2 * 32 + kq * 8 + jj;
        w1b[e] = (__bf16)w1[k * 16 + c16];
    }
}

// ---------------- init: h = relu(x @ lin0_w + lin0_b) ----------------
__global__ __launch_bounds__(256) void k_init(const float* __restrict__ x, const float* __restrict__ w,
                                              const float* __restrict__ b, float* __restrict__ h) {
    __shared__ float s_w[F_IN * DIM];
    int tid = threadIdx.x;
    for (int i = tid; i < F_IN * DIM; i += 256) s_w[i] = w[i];
    int node = blockIdx.x * 16 + (tid >> 4);
    int c4 = tid & 15;
    const float4* xp = (const float4*)(x + (size_t)node * F_IN);
    float4 x0 = xp[0], x1 = xp[1], x2 = xp[2], x3 = xp[3];
    float xa[16] = {x0.x, x0.y, x0.z, x0.w, x1.x, x1.y, x1.z, x1.w,
                    x2.x, x2.y, x2.z, x2.w, x3.x, x3.y, x3.z, x3.w};
    __syncthreads();
    float4 acc = ((const float4*)b)[c4];
    const float4* w4 = (const float4*)s_w;
#pragma unroll
    for (int k = 0; k < 16; ++k) {
        float4 wv = w4[k * 16 + c4];
        FMA4(acc, xa[k], wv);
    }
    acc.x = fmaxf(acc.x, 0.f); acc.y = fmaxf(acc.y, 0.f);
    acc.z = fmaxf(acc.z, 0.f); acc.w = fmaxf(acc.w, 0.f);
    *(float4*)(h + (size_t)node * DIM + c4 * 4) = acc;
}

// ---------------- out1 = h @ lin1_w + lin1_b (once, pre-loop) ----------------
__global__ __launch_bounds__(256) void k_lin1(const float* __restrict__ h, const float* __restrict__ w,
                                              const float* __restrict__ b, float* __restrict__ out1) {
    __shared__ float s_h[64 * 68];
    int tid = threadIdx.x;
    int nb = blockIdx.x * 64;
    const float4* hp = (const float4*)(h + (size_t)nb * 64);
    for (int i = tid; i < 64 * 16; i += 256) {
        int n = i >> 4, q4 = i & 15;
        float4 v = hp[i];
        *(float4*)&s_h[n * 68 + q4 * 4] = v;
    }
    int ct = tid & 15;
    float wcol[64];
#pragma unroll
    for (int q = 0; q < 64; ++q) wcol[q] = w[q * 16 + ct];
    float bias = b[ct];
    __syncthreads();
    int ng = tid >> 4;
#pragma unroll
    for (int rep = 0; rep < 4; ++rep) {
        int nl = ng + 16 * rep;
        float acc = bias;
#pragma unroll
        for (int q4 = 0; q4 < 16; ++q4) {
            float4 hv = *(const float4*)&s_h[nl * 68 + q4 * 4];
            acc = fmaf(hv.x, wcol[4 * q4 + 0], acc);
            acc = fmaf(hv.y, wcol[4 * q4 + 1], acc);
            acc = fmaf(hv.z, wcol[4 * q4 + 2], acc);
            acc = fmaf(hv.w, wcol[4 * q4 + 3], acc);
        }
        out1[(size_t)(nb + nl) * 16 + ct] = acc;
    }
}

// ---------------- node v8: 4-chain register gather + MFMA GRU ----------------
// Gather: 16-lane group owns 4 nodes (g + 16r), advances 4 independent edge
// chains per round with clamped unpredicated loads -> 4-deep MLP, no atomics,
// no bank conflicts. S*inv -> bf16 straight into s_X. Then the R12 pipeline:
// o2 = X2@B2 (K=96), gates GEMM, GRU epilogue, fused lin1. LDS 59392 B.
__attribute__((amdgpu_waves_per_eu(2)))
__global__ __launch_bounds__(256) void k_node(
    const float* __restrict__ out1_in, float* __restrict__ out1_out,
    const int* __restrict__ csr_src, const float4* __restrict__ csr_ea,
    const int* __restrict__ row_ptr, const float* __restrict__ inv_cnt,
    float* __restrict__ h, const __bf16* __restrict__ Wb, const __bf16* __restrict__ B2b,
    const __bf16* __restrict__ w1b, const float* __restrict__ conv_b,
    const float* __restrict__ bih, const float* __restrict__ lin1_b)
{
    __shared__ __align__(16) __bf16 s_X[64 * 104];   // 13312 B
    __shared__ __align__(16) __bf16 s_W[40 * 512];   // 40960 B
    __shared__ __align__(16) __bf16 s_B2[3 * 512];   //  3072 B
    __shared__ __align__(16) __bf16 s_w1[1024];      //  2048 B
    int tid = threadIdx.x;
    int nb = blockIdx.x * 64;
    int lane = tid & 63, w = tid >> 6;
    int c16 = lane & 15, lq = lane >> 4;
    int nwb = nb + w * 16;

    // cooperative staging of weight tiles
    {
        const float4* src = (const float4*)Wb;
        float4* dst = (float4*)s_W;
#pragma unroll
        for (int i = 0; i < 10; ++i) dst[tid + 256 * i] = src[tid + 256 * i];
        for (int i = tid; i < 320; i += 256) {
            if (i < 192) ((float4*)s_B2)[i] = ((const float4*)B2b)[i];
            else ((float4*)s_w1)[i - 192] = ((const float4*)w1b)[i - 192];
        }
    }
    // own out1 row -> X2[.][0..15]
    {
        int n = lane >> 2, k4 = lane & 3;
        float4 v = *(const float4*)(out1_in + (size_t)(nwb + n) * 16 + k4 * 4);
        __bf16* p = &s_X[(w * 16 + n) * 104 + k4 * 4];
        p[0] = (__bf16)v.x; p[1] = (__bf16)v.y; p[2] = (__bf16)v.z; p[3] = (__bf16)v.w;
    }

    // gather: 16 groups x 4 interleaved node-chains, register accumulation
    {
        int g = tid >> 4, k = tid & 15;
        int ec[4], ee[4];
        float S0[4] = {0.f,0.f,0.f,0.f}, S1[4] = {0.f,0.f,0.f,0.f}, S2[4] = {0.f,0.f,0.f,0.f},
              S3[4] = {0.f,0.f,0.f,0.f}, S4[4] = {0.f,0.f,0.f,0.f};
#pragma unroll
        for (int r = 0; r < 4; ++r) {
            int n = nb + g + 16 * r;
            ec[r] = row_ptr[n]; ee[r] = row_ptr[n + 1];
        }
        bool more = (ec[0] < ee[0]) | (ec[1] < ee[1]) | (ec[2] < ee[2]) | (ec[3] < ee[3]);
        while (more) {
            int vsrc[4]; float4 av[4]; float xv[4]; bool act[4];
#pragma unroll
            for (int r = 0; r < 4; ++r) {
                act[r] = ec[r] < ee[r];
                int e = min(ec[r], N_EDGES - 1);     // clamped, always-issued
                vsrc[r] = csr_src[e];
                av[r] = csr_ea[e];
            }
#pragma unroll
            for (int r = 0; r < 4; ++r)
                xv[r] = out1_in[(size_t)(vsrc[r] & 0xFFFFF) * 16 + k];
#pragma unroll
            for (int r = 0; r < 4; ++r) {
                if (act[r]) {
                    S0[r] += xv[r];
                    S1[r] = fmaf(av[r].x, xv[r], S1[r]);
                    S2[r] = fmaf(av[r].y, xv[r], S2[r]);
                    S3[r] = fmaf(av[r].z, xv[r], S3[r]);
                    S4[r] = fmaf(av[r].w, xv[r], S4[r]);
                    ec[r]++;
                }
            }
            more = (ec[0] < ee[0]) | (ec[1] < ee[1]) | (ec[2] < ee[2]) | (ec[3] < ee[3]);
        }
#pragma unroll
        for (int r = 0; r < 4; ++r) {
            int nl = g + 16 * r;
            float inv = inv_cnt[nb + nl];
            __bf16* p = &s_X[nl * 104];
            p[16 + k] = (__bf16)(S0[r] * inv);
            p[32 + k] = (__bf16)(S1[r] * inv);
            p[48 + k] = (__bf16)(S2[r] * inv);
            p[64 + k] = (__bf16)(S3[r] * inv);
            p[80 + k] = (__bf16)(S4[r] * inv);
        }
    }
    __syncthreads();

    // phase 2: o2 = X2 @ B2 + conv_b (K=96)
    float cb = conv_b[c16];
    f32x4 co2 = (f32x4){cb, cb, cb, cb};
#pragma unroll
    for (int kk = 0; kk < 3; ++kk) {
        bf16x8 a = *(const bf16x8*)&s_X[(w * 16 + c16) * 104 + kk * 32 + lq * 8];
        bf16x8 b = *(const bf16x8*)&s_B2[kk * 512 + lane * 8];
        co2 = __builtin_amdgcn_mfma_f32_16x16x32_bf16(a, b, co2, 0, 0, 0);
    }

    // phase 3a: rebuild X = [o2(16) | h(64) | 1 | 0..] (wave-own rows, same-wave DS order)
#pragma unroll
    for (int jr = 0; jr < 4; ++jr)
        s_X[(w * 16 + 4 * lq + jr) * 104 + c16] = (__bf16)co2[jr];
    {
        const float4* hsrc = (const float4*)(h + (size_t)nwb * 64);
#pragma unroll
        for (int ii = 0; ii < 4; ++ii) {
            int idx = lane + 64 * ii;
            int n = idx >> 4, d4 = idx & 15;
            float4 v = hsrc[idx];
            __bf16* p = &s_X[(w * 16 + n) * 104 + 16 + d4 * 4];
            p[0] = (__bf16)v.x; p[1] = (__bf16)v.y; p[2] = (__bf16)v.z; p[3] = (__bf16)v.w;
        }
    }
    {
        int n = lane >> 2, c0 = 80 + (lane & 3) * 4;
#pragma unroll
        for (int q = 0; q < 4; ++q)
            s_X[(w * 16 + n) * 104 + c0 + q] = (c0 + q == 80) ? (__bf16)1.0f : (__bf16)0.0f;
    }

    // phase 3b: gates GEMM
    f32x4 acc[12], ani4[4];
#pragma unroll
    for (int i = 0; i < 12; ++i) acc[i] = (f32x4){0.f, 0.f, 0.f, 0.f};
#pragma unroll
    for (int i = 0; i < 4; ++i) ani4[i] = (f32x4){0.f, 0.f, 0.f, 0.f};
    bf16x8 af[3];
#pragma unroll
    for (int kk = 0; kk < 3; ++kk)
        af[kk] = *(const bf16x8*)&s_X[(w * 16 + c16) * 104 + kk * 32 + lq * 8];
#pragma unroll
    for (int ct = 0; ct < 12; ++ct) {
#pragma unroll
        for (int kk = 0; kk < 3; ++kk) {
            bf16x8 bf = *(const bf16x8*)&s_W[(ct * 3 + kk) * 512 + lane * 8];
            acc[ct] = __builtin_amdgcn_mfma_f32_16x16x32_bf16(af[kk], bf, acc[ct], 0, 0, 0);
        }
    }
#pragma unroll
    for (int ct8 = 0; ct8 < 4; ++ct8) {
        bf16x8 bf = *(const bf16x8*)&s_W[(36 + ct8) * 512 + lane * 8];
        ani4[ct8] = __builtin_amdgcn_mfma_f32_16x16x32_bf16(af[0], bf, ani4[ct8], 0, 0, 0);
    }

    // GRU epilogue
    float hn[4][4];
#pragma unroll
    for (int ct = 0; ct < 4; ++ct) {
        float bni = bih[128 + ct * 16 + c16];
#pragma unroll
        for (int jr = 0; jr < 4; ++jr) {
            int node = nb + w * 16 + 4 * lq + jr;
            float hold = h[(size_t)node * 64 + ct * 16 + c16];
            float rr = 1.f / (1.f + __expf(-acc[ct][jr]));
            float zz = 1.f / (1.f + __expf(-acc[4 + ct][jr]));
            float xx = fmaf(rr, acc[8 + ct][jr], ani4[ct][jr] + bni);
            float ax = fabsf(xx);
            float ee = __expf(-2.f * ax);
            float ncv = __builtin_copysignf((1.f - ee) / (1.f + ee), xx);
            float hv = fmaf(zz, hold - ncv, ncv);
            hn[ct][jr] = hv;
            h[(size_t)node * 64 + ct * 16 + c16] = hv;
        }
    }
#pragma unroll
    for (int ct = 0; ct < 4; ++ct)
#pragma unroll
        for (int jr = 0; jr < 4; ++jr)
            s_X[(w * 16 + 4 * lq + jr) * 104 + 16 + ct * 16 + c16] = (__bf16)hn[ct][jr];

    // fused lin1 -> out1_out
    f32x4 o1acc = (f32x4){0.f, 0.f, 0.f, 0.f};
#pragma unroll
    for (int kk = 0; kk < 2; ++kk) {
        bf16x8 a = *(const bf16x8*)&s_X[(w * 16 + c16) * 104 + 16 + kk * 32 + lq * 8];
        bf16x8 b = *(const bf16x8*)&s_w1[kk * 512 + lane * 8];
        o1acc = __builtin_amdgcn_mfma_f32_16x16x32_bf16(a, b, o1acc, 0, 0, 0);
    }
    float lb = lin1_b[c16];
#pragma unroll
    for (int jr = 0; jr < 4; ++jr) {
        int node = nb + w * 16 + 4 * lq + jr;
        out1_out[(size_t)node * 16 + c16] = o1acc[jr] + lb;
    }
}

// ---------------- final ----------------
__global__ __launch_bounds__(256) void k_final(const float* __restrict__ h, const float* __restrict__ w2,
                                               const int* __restrict__ batch, float* __restrict__ out) {
    int i = blockIdx.x * 4 + (threadIdx.x >> 6);
    int lane = threadIdx.x & 63;
    float v = h[(size_t)i * DIM + lane] * w2[lane];
#pragma unroll
    for (int off = 32; off > 0; off >>= 1) v += __shfl_down(v, off, 64);
    if (lane == 0) atomicAdd(&out[batch[i]], v);
}

extern "C" void kernel_launch(void* const* d_in, const int* in_sizes, int n_in,
                              void* d_out, int out_size, void* d_ws, size_t ws_size,
                              hipStream_t stream) {
    const float* x        = (const float*)d_in[0];
    const float* edge_attr= (const float*)d_in[1];
    const float* lin0_w   = (const float*)d_in[2];
    const float* lin0_b   = (const float*)d_in[3];
    const float* nn1_w    = (const float*)d_in[4];
    const float* nn1_b    = (const float*)d_in[5];
    const float* root_w   = (const float*)d_in[6];
    const float* conv_b   = (const float*)d_in[7];
    const float* gru_w_ih = (const float*)d_in[8];
    const float* gru_w_hh = (const float*)d_in[9];
    const float* gru_b_ih = (const float*)d_in[10];
    const float* gru_b_hh = (const float*)d_in[11];
    const float* lin1_w   = (const float*)d_in[12];
    const float* lin1_b   = (const float*)d_in[13];
    const float* lin2_w   = (const float*)d_in[14];
    const int*   ei       = (const int*)d_in[15];
    const int*   batch    = (const int*)d_in[16];
    float* out = (float*)d_out;

    char* p = (char*)d_ws;
    float*  h       = (float*)p;            p += (size_t)N_NODES * DIM * 4;
    float*  out1A   = (float*)p;            p += (size_t)N_NODES * DNN * 4;
    float*  out1B   = (float*)p;            p += (size_t)N_NODES * DNN * 4;
    float4* csr_ea  = (float4*)p;           p += (size_t)N_EDGES * 16;
    __bf16* Wb      = (__bf16*)p;           p += (size_t)WB_SZ * 2;
    __bf16* B2b     = (__bf16*)p;           p += 1536 * 2;
    __bf16* w1b     = (__bf16*)p;           p += 1024 * 2;
    int*    cnt     = (int*)p;              p += (size_t)N_NODES * 4;
    float*  inv_cnt = (float*)p;            p += (size_t)N_NODES * 4;
    int*    row_ptr = (int*)p;              p += (size_t)(N_NODES + 16) * 4;
    int*    cursor  = (int*)p;              p += (size_t)N_NODES * 4;
    int*    excl    = (int*)p;              p += (size_t)N_NODES * 4;
    int*    bsum    = (int*)p;              p += 512 * 4;
    int*    boff    = (int*)p;              p += 512 * 4;
    int*    csr_src = (int*)p;              p += (size_t)N_EDGES * 4;

    hipMemsetAsync(d_out, 0, (size_t)NG * 4, stream);
    hipMemsetAsync(cnt, 0, (size_t)N_NODES * 4, stream);
    k_prep<<<330, 256, 0, stream>>>(gru_w_ih, gru_w_hh, root_w, lin1_w, gru_b_ih, gru_b_hh,
                                    nn1_w, nn1_b, Wb, B2b, w1b);
    k_degree<<<N_EDGES / 256, 256, 0, stream>>>(ei, cnt);
    k_scanA<<<N_NODES / 256, 256, 0, stream>>>(cnt, excl, bsum);
    k_scanB<<<1, 256, 0, stream>>>(bsum, boff);
    k_scanC<<<N_NODES / 256, 256, 0, stream>>>(excl, boff, row_ptr, cursor);
    k_scatter<<<N_EDGES / 256, 256, 0, stream>>>(ei, edge_attr, cursor, csr_src, csr_ea);
    k_invcnt<<<N_NODES / 256, 256, 0, stream>>>(cnt, inv_cnt);
    k_init<<<N_NODES / 16, 256, 0, stream>>>(x, lin0_w, lin0_b, h);
    k_lin1<<<N_NODES / 64, 256, 0, stream>>>(h, lin1_w, lin1_b, out1A);

    for (int it = 0; it < N_ITERS; ++it) {
        int j = it >> 1;   // GRU index (NL2 = 2)
        const float* o_in = (it & 1) ? out1B : out1A;
        float*       o_out= (it & 1) ? out1A : out1B;
        k_node<<<N_NODES / 64, 256, 0, stream>>>(o_in, o_out, csr_src, csr_ea, row_ptr, inv_cnt,
                                                 h, Wb + (size_t)j * 40 * 512, B2b, w1b,
                                                 conv_b, gru_b_ih + (size_t)j * 192, lin1_b);
    }
    k_final<<<N_NODES / 4, 256, 0, stream>>>(h, lin2_w, batch, out);
}

// Round 15
// 496.078 us; speedup vs baseline: 4.3978x; 1.3477x over previous
//
#include <hip/hip_runtime.h>
#include <hip/hip_bf16.h>

#define N_NODES 131072
#define N_EDGES 524288
#define F_IN 16
#define DIM 64
#define DNN 16
#define BK 4
#define NG 8192
#define N_ITERS 8   // NL1*NL2

typedef __bf16 bf16x8 __attribute__((ext_vector_type(8)));
typedef float f32x4 __attribute__((ext_vector_type(4)));

#define FMA4(A_, S_, W_) { (A_).x = fmaf((S_), (W_).x, (A_).x); (A_).y = fmaf((S_), (W_).y, (A_).y); \
                           (A_).z = fmaf((S_), (W_).z, (A_).z); (A_).w = fmaf((S_), (W_).w, (A_).w); }

// ---------------- degree (int) ----------------
__global__ __launch_bounds__(256) void k_degree(const int* __restrict__ ei, int* __restrict__ cnt) {
    int e = blockIdx.x * 256 + threadIdx.x;
    atomicAdd(&cnt[ei[N_EDGES + e]], 1);
}

__global__ __launch_bounds__(256) void k_invcnt(const int* __restrict__ cnt, float* __restrict__ inv) {
    int i = blockIdx.x * 256 + threadIdx.x;
    inv[i] = 1.0f / (float)max(cnt[i], 1);
}

// ---------------- CSR scan ----------------
__global__ __launch_bounds__(256) void k_scanA(const int* __restrict__ cnt, int* __restrict__ excl,
                                               int* __restrict__ bsum) {
    __shared__ int a[256], b[256];
    int t = threadIdx.x, gid = blockIdx.x * 256 + t;
    int c = cnt[gid];
    a[t] = c; __syncthreads();
    int *s = a, *d = b;
#pragma unroll
    for (int off = 1; off < 256; off <<= 1) {
        d[t] = s[t] + (t >= off ? s[t - off] : 0);
        __syncthreads();
        int* tmp = s; s = d; d = tmp;
    }
    excl[gid] = s[t] - c;
    if (t == 255) bsum[blockIdx.x] = s[255];
}

__global__ __launch_bounds__(256) void k_scanB(const int* __restrict__ bsum, int* __restrict__ boff) {
    __shared__ int a[512], b[512];
    int t = threadIdx.x;
    a[t] = bsum[t]; a[t + 256] = bsum[t + 256];
    __syncthreads();
    int *s = a, *d = b;
#pragma unroll
    for (int off = 1; off < 512; off <<= 1) {
        d[t] = s[t] + (t >= off ? s[t - off] : 0);
        int i2 = t + 256;
        d[i2] = s[i2] + (i2 >= off ? s[i2 - off] : 0);
        __syncthreads();
        int* tmp = s; s = d; d = tmp;
    }
    boff[t] = t ? s[t - 1] : 0;
    boff[t + 256] = s[t + 255];
}

__global__ __launch_bounds__(256) void k_scanC(const int* __restrict__ excl, const int* __restrict__ boff,
                                               int* __restrict__ row_ptr, int* __restrict__ cursor) {
    int gid = blockIdx.x * 256 + threadIdx.x;
    int v = excl[gid] + boff[gid >> 8];
    row_ptr[gid] = v;
    cursor[gid] = v;
    if (gid == 0) row_ptr[N_NODES] = N_EDGES;
}

__global__ __launch_bounds__(256) void k_scatter(const int* __restrict__ ei, const float* __restrict__ ea,
                                                 int* __restrict__ cursor, int* __restrict__ csr_src,
                                                 float4* __restrict__ csr_ea) {
    int e = blockIdx.x * 256 + threadIdx.x;
    int dst = ei[N_EDGES + e];
    int pos = atomicAdd(&cursor[dst], 1);
    csr_src[pos] = ei[e];
    csr_ea[pos] = ((const float4*)ea)[e];
}

// ---------------- prep: bf16 B-fragment weight tiles ----------------
// Wb: gates tiles. B2b: o2 tiles K=96 (rows 0..15 root_w, 16..31 nn1b, 32..95 nn1w).
#define WB_SZ (4 * 40 * 512)
__global__ __launch_bounds__(256) void k_prep(const float* __restrict__ wih, const float* __restrict__ whh,
                                              const float* __restrict__ rw, const float* __restrict__ w1,
                                              const float* __restrict__ bih, const float* __restrict__ bhh,
                                              const float* __restrict__ nn1w, const float* __restrict__ nn1b,
                                              __bf16* __restrict__ Wb, __bf16* __restrict__ B2b,
                                              __bf16* __restrict__ w1b) {
    int idx = blockIdx.x * 256 + threadIdx.x;
    if (idx < WB_SZ) {
        int j = idx / 20480, r = idx % 20480;
        int t = r >> 9, e = r & 511;
        int jj = e & 7, c16 = (e >> 3) & 15, kq = e >> 7;
        int ct, kk; bool nih = false;
        if (t < 36) { ct = t / 3; kk = t % 3; } else { ct = 8 + (t - 36); kk = 0; nih = true; }
        int k = kk * 32 + kq * 8 + jj;
        int c = ct * 16 + c16;
        bool ngate = ct >= 8;
        float v = 0.f;
        if (nih) {
            if (k < 16) v = wih[((size_t)j * 192 + c) * 16 + k];
        } else {
            if (k < 16) v = ngate ? 0.f : wih[((size_t)j * 192 + c) * 16 + k];
            else if (k < 80) v = whh[((size_t)j * 192 + c) * 64 + (k - 16)];
            else if (k == 80) v = ngate ? bhh[j * 192 + c] : (bih[j * 192 + c] + bhh[j * 192 + c]);
        }
        Wb[idx] = (__bf16)v;
    } else if (idx < WB_SZ + 1536) {
        int e = idx - WB_SZ;
        int t = e >> 9, ee = e & 511;
        int jj = ee & 7, c16 = (ee >> 3) & 15, kq = ee >> 7;
        int krow = t * 32 + kq * 8 + jj;
        float v;
        if (krow < 16) v = rw[krow * 16 + c16];
        else {
            int i = (krow - 16) >> 4, kk = (krow - 16) & 15;
            v = (i == 0) ? nn1b[kk * 16 + c16] : nn1w[(i - 1) * 256 + kk * 16 + c16];
        }
        B2b[e] = (__bf16)v;
    } else if (idx < WB_SZ + 1536 + 1024) {
        int e = idx - (WB_SZ + 1536);
        int t2 = e >> 9, ee = e & 511;
        int jj = ee & 7, c16 = (ee >> 3) & 15, kq = ee >> 7;
        int k = t2 * 32 + kq * 8 + jj;
        w1b[e] = (__bf16)w1[k * 16 + c16];
    }
}

// ---------------- init: h = relu(x @ lin0_w + lin0_b) ----------------
__global__ __launch_bounds__(256) void k_init(const float* __restrict__ x, const float* __restrict__ w,
                                              const float* __restrict__ b, float* __restrict__ h) {
    __shared__ float s_w[F_IN * DIM];
    int tid = threadIdx.x;
    for (int i = tid; i < F_IN * DIM; i += 256) s_w[i] = w[i];
    int node = blockIdx.x * 16 + (tid >> 4);
    int c4 = tid & 15;
    const float4* xp = (const float4*)(x + (size_t)node * F_IN);
    float4 x0 = xp[0], x1 = xp[1], x2 = xp[2], x3 = xp[3];
    float xa[16] = {x0.x, x0.y, x0.z, x0.w, x1.x, x1.y, x1.z, x1.w,
                    x2.x, x2.y, x2.z, x2.w, x3.x, x3.y, x3.z, x3.w};
    __syncthreads();
    float4 acc = ((const float4*)b)[c4];
    const float4* w4 = (const float4*)s_w;
#pragma unroll
    for (int k = 0; k < 16; ++k) {
        float4 wv = w4[k * 16 + c4];
        FMA4(acc, xa[k], wv);
    }
    acc.x = fmaxf(acc.x, 0.f); acc.y = fmaxf(acc.y, 0.f);
    acc.z = fmaxf(acc.z, 0.f); acc.w = fmaxf(acc.w, 0.f);
    *(float4*)(h + (size_t)node * DIM + c4 * 4) = acc;
}

// ---------------- out1 = h @ lin1_w + lin1_b (once, pre-loop) ----------------
__global__ __launch_bounds__(256) void k_lin1(const float* __restrict__ h, const float* __restrict__ w,
                                              const float* __restrict__ b, float* __restrict__ out1) {
    __shared__ float s_h[64 * 68];
    int tid = threadIdx.x;
    int nb = blockIdx.x * 64;
    const float4* hp = (const float4*)(h + (size_t)nb * 64);
    for (int i = tid; i < 64 * 16; i += 256) {
        int n = i >> 4, q4 = i & 15;
        float4 v = hp[i];
        *(float4*)&s_h[n * 68 + q4 * 4] = v;
    }
    int ct = tid & 15;
    float wcol[64];
#pragma unroll
    for (int q = 0; q < 64; ++q) wcol[q] = w[q * 16 + ct];
    float bias = b[ct];
    __syncthreads();
    int ng = tid >> 4;
#pragma unroll
    for (int rep = 0; rep < 4; ++rep) {
        int nl = ng + 16 * rep;
        float acc = bias;
#pragma unroll
        for (int q4 = 0; q4 < 16; ++q4) {
            float4 hv = *(const float4*)&s_h[nl * 68 + q4 * 4];
            acc = fmaf(hv.x, wcol[4 * q4 + 0], acc);
            acc = fmaf(hv.y, wcol[4 * q4 + 1], acc);
            acc = fmaf(hv.z, wcol[4 * q4 + 2], acc);
            acc = fmaf(hv.w, wcol[4 * q4 + 3], acc);
        }
        out1[(size_t)(nb + nl) * 16 + ct] = acc;
    }
}

// ---------------- node v9: 128-node / 512-thread block (2x waves/SIMD) ----------------
// Same structure as v8, but 8 waves/block amortize the 40KB s_W: LDS 72.7KB ->
// 2 blocks/CU -> 16 waves/CU = 4/SIMD (was 2/SIMD). Each wave owns 16 nodes;
// gather = 32 groups x 4 interleaved chains, register accumulation, no atomics.
__attribute__((amdgpu_waves_per_eu(2, 4)))
__global__ __launch_bounds__(512) void k_node(
    const float* __restrict__ out1_in, float* __restrict__ out1_out,
    const int* __restrict__ csr_src, const float4* __restrict__ csr_ea,
    const int* __restrict__ row_ptr, const float* __restrict__ inv_cnt,
    float* __restrict__ h, const __bf16* __restrict__ Wb, const __bf16* __restrict__ B2b,
    const __bf16* __restrict__ w1b, const float* __restrict__ conv_b,
    const float* __restrict__ bih, const float* __restrict__ lin1_b)
{
    __shared__ __align__(16) __bf16 s_X[128 * 104];  // 26624 B
    __shared__ __align__(16) __bf16 s_W[40 * 512];   // 40960 B
    __shared__ __align__(16) __bf16 s_B2[3 * 512];   //  3072 B
    __shared__ __align__(16) __bf16 s_w1[1024];      //  2048 B  (total 72704)
    int tid = threadIdx.x;
    int nb = blockIdx.x * 128;
    int lane = tid & 63, w = tid >> 6;               // w = 0..7
    int c16 = lane & 15, lq = lane >> 4;
    int nwb = nb + w * 16;
    int xrow = w * 16;                               // this wave's s_X row base

    // cooperative staging of weight tiles (512 threads)
    {
        const float4* src = (const float4*)Wb;
        float4* dst = (float4*)s_W;
#pragma unroll
        for (int i = 0; i < 5; ++i) dst[tid + 512 * i] = src[tid + 512 * i];
        if (tid < 192) ((float4*)s_B2)[tid] = ((const float4*)B2b)[tid];
        else if (tid < 320) ((float4*)s_w1)[tid - 192] = ((const float4*)w1b)[tid - 192];
    }
    // own out1 row -> X2[.][0..15] (per-wave)
    {
        int n = lane >> 2, k4 = lane & 3;
        float4 v = *(const float4*)(out1_in + (size_t)(nwb + n) * 16 + k4 * 4);
        __bf16* p = &s_X[(xrow + n) * 104 + k4 * 4];
        p[0] = (__bf16)v.x; p[1] = (__bf16)v.y; p[2] = (__bf16)v.z; p[3] = (__bf16)v.w;
    }

    // gather: 32 groups x 4 interleaved node-chains, register accumulation
    {
        int g = tid >> 4, k = tid & 15;              // g = 0..31
        int ec[4], ee[4];
        float S0[4] = {0.f,0.f,0.f,0.f}, S1[4] = {0.f,0.f,0.f,0.f}, S2[4] = {0.f,0.f,0.f,0.f},
              S3[4] = {0.f,0.f,0.f,0.f}, S4[4] = {0.f,0.f,0.f,0.f};
#pragma unroll
        for (int r = 0; r < 4; ++r) {
            int n = nb + g + 32 * r;
            ec[r] = row_ptr[n]; ee[r] = row_ptr[n + 1];
        }
        bool more = (ec[0] < ee[0]) | (ec[1] < ee[1]) | (ec[2] < ee[2]) | (ec[3] < ee[3]);
        while (more) {
            int vsrc[4]; float4 av[4]; float xv[4]; bool act[4];
#pragma unroll
            for (int r = 0; r < 4; ++r) {
                act[r] = ec[r] < ee[r];
                int e = min(ec[r], N_EDGES - 1);     // clamped, always-issued
                vsrc[r] = csr_src[e];
                av[r] = csr_ea[e];
            }
#pragma unroll
            for (int r = 0; r < 4; ++r)
                xv[r] = out1_in[(size_t)(vsrc[r] & 0xFFFFF) * 16 + k];
#pragma unroll
            for (int r = 0; r < 4; ++r) {
                if (act[r]) {
                    S0[r] += xv[r];
                    S1[r] = fmaf(av[r].x, xv[r], S1[r]);
                    S2[r] = fmaf(av[r].y, xv[r], S2[r]);
                    S3[r] = fmaf(av[r].z, xv[r], S3[r]);
                    S4[r] = fmaf(av[r].w, xv[r], S4[r]);
                    ec[r]++;
                }
            }
            more = (ec[0] < ee[0]) | (ec[1] < ee[1]) | (ec[2] < ee[2]) | (ec[3] < ee[3]);
        }
#pragma unroll
        for (int r = 0; r < 4; ++r) {
            int nl = g + 32 * r;
            float inv = inv_cnt[nb + nl];
            __bf16* p = &s_X[nl * 104];
            p[16 + k] = (__bf16)(S0[r] * inv);
            p[32 + k] = (__bf16)(S1[r] * inv);
            p[48 + k] = (__bf16)(S2[r] * inv);
            p[64 + k] = (__bf16)(S3[r] * inv);
            p[80 + k] = (__bf16)(S4[r] * inv);
        }
    }
    __syncthreads();

    // phase 2: o2 = X2 @ B2 + conv_b (K=96)
    float cb = conv_b[c16];
    f32x4 co2 = (f32x4){cb, cb, cb, cb};
#pragma unroll
    for (int kk = 0; kk < 3; ++kk) {
        bf16x8 a = *(const bf16x8*)&s_X[(xrow + c16) * 104 + kk * 32 + lq * 8];
        bf16x8 b = *(const bf16x8*)&s_B2[kk * 512 + lane * 8];
        co2 = __builtin_amdgcn_mfma_f32_16x16x32_bf16(a, b, co2, 0, 0, 0);
    }

    // phase 3a: rebuild X = [o2(16) | h(64) | 1 | 0..] (wave-own rows, same-wave DS order)
#pragma unroll
    for (int jr = 0; jr < 4; ++jr)
        s_X[(xrow + 4 * lq + jr) * 104 + c16] = (__bf16)co2[jr];
    {
        const float4* hsrc = (const float4*)(h + (size_t)nwb * 64);
#pragma unroll
        for (int ii = 0; ii < 4; ++ii) {
            int idx = lane + 64 * ii;
            int n = idx >> 4, d4 = idx & 15;
            float4 v = hsrc[idx];
            __bf16* p = &s_X[(xrow + n) * 104 + 16 + d4 * 4];
            p[0] = (__bf16)v.x; p[1] = (__bf16)v.y; p[2] = (__bf16)v.z; p[3] = (__bf16)v.w;
        }
    }
    {
        int n = lane >> 2, c0 = 80 + (lane & 3) * 4;
#pragma unroll
        for (int q = 0; q < 4; ++q)
            s_X[(xrow + n) * 104 + c0 + q] = (c0 + q == 80) ? (__bf16)1.0f : (__bf16)0.0f;
    }

    // phase 3b: gates GEMM
    f32x4 acc[12], ani4[4];
#pragma unroll
    for (int i = 0; i < 12; ++i) acc[i] = (f32x4){0.f, 0.f, 0.f, 0.f};
#pragma unroll
    for (int i = 0; i < 4; ++i) ani4[i] = (f32x4){0.f, 0.f, 0.f, 0.f};
    bf16x8 af[3];
#pragma unroll
    for (int kk = 0; kk < 3; ++kk)
        af[kk] = *(const bf16x8*)&s_X[(xrow + c16) * 104 + kk * 32 + lq * 8];
#pragma unroll
    for (int ct = 0; ct < 12; ++ct) {
#pragma unroll
        for (int kk = 0; kk < 3; ++kk) {
            bf16x8 bf = *(const bf16x8*)&s_W[(ct * 3 + kk) * 512 + lane * 8];
            acc[ct] = __builtin_amdgcn_mfma_f32_16x16x32_bf16(af[kk], bf, acc[ct], 0, 0, 0);
        }
    }
#pragma unroll
    for (int ct8 = 0; ct8 < 4; ++ct8) {
        bf16x8 bf = *(const bf16x8*)&s_W[(36 + ct8) * 512 + lane * 8];
        ani4[ct8] = __builtin_amdgcn_mfma_f32_16x16x32_bf16(af[0], bf, ani4[ct8], 0, 0, 0);
    }

    // GRU epilogue
    float hn[4][4];
#pragma unroll
    for (int ct = 0; ct < 4; ++ct) {
        float bni = bih[128 + ct * 16 + c16];
#pragma unroll
        for (int jr = 0; jr < 4; ++jr) {
            int node = nwb + 4 * lq + jr;
            float hold = h[(size_t)node * 64 + ct * 16 + c16];
            float rr = 1.f / (1.f + __expf(-acc[ct][jr]));
            float zz = 1.f / (1.f + __expf(-acc[4 + ct][jr]));
            float xx = fmaf(rr, acc[8 + ct][jr], ani4[ct][jr] + bni);
            float ax = fabsf(xx);
            float ee = __expf(-2.f * ax);
            float ncv = __builtin_copysignf((1.f - ee) / (1.f + ee), xx);
            float hv = fmaf(zz, hold - ncv, ncv);
            hn[ct][jr] = hv;
            h[(size_t)node * 64 + ct * 16 + c16] = hv;
        }
    }
#pragma unroll
    for (int ct = 0; ct < 4; ++ct)
#pragma unroll
        for (int jr = 0; jr < 4; ++jr)
            s_X[(xrow + 4 * lq + jr) * 104 + 16 + ct * 16 + c16] = (__bf16)hn[ct][jr];

    // fused lin1 -> out1_out
    f32x4 o1acc = (f32x4){0.f, 0.f, 0.f, 0.f};
#pragma unroll
    for (int kk = 0; kk < 2; ++kk) {
        bf16x8 a = *(const bf16x8*)&s_X[(xrow + c16) * 104 + 16 + kk * 32 + lq * 8];
        bf16x8 b = *(const bf16x8*)&s_w1[kk * 512 + lane * 8];
        o1acc = __builtin_amdgcn_mfma_f32_16x16x32_bf16(a, b, o1acc, 0, 0, 0);
    }
    float lb = lin1_b[c16];
#pragma unroll
    for (int jr = 0; jr < 4; ++jr) {
        int node = nwb + 4 * lq + jr;
        out1_out[(size_t)node * 16 + c16] = o1acc[jr] + lb;
    }
}

// ---------------- final ----------------
__global__ __launch_bounds__(256) void k_final(const float* __restrict__ h, const float* __restrict__ w2,
                                               const int* __restrict__ batch, float* __restrict__ out) {
    int i = blockIdx.x * 4 + (threadIdx.x >> 6);
    int lane = threadIdx.x & 63;
    float v = h[(size_t)i * DIM + lane] * w2[lane];
#pragma unroll
    for (int off = 32; off > 0; off >>= 1) v += __shfl_down(v, off, 64);
    if (lane == 0) atomicAdd(&out[batch[i]], v);
}

extern "C" void kernel_launch(void* const* d_in, const int* in_sizes, int n_in,
                              void* d_out, int out_size, void* d_ws, size_t ws_size,
                              hipStream_t stream) {
    const float* x        = (const float*)d_in[0];
    const float* edge_attr= (const float*)d_in[1];
    const float* lin0_w   = (const float*)d_in[2];
    const float* lin0_b   = (const float*)d_in[3];
    const float* nn1_w    = (const float*)d_in[4];
    const float* nn1_b    = (const float*)d_in[5];
    const float* root_w   = (const float*)d_in[6];
    const float* conv_b   = (const float*)d_in[7];
    const float* gru_w_ih = (const float*)d_in[8];
    const float* gru_w_hh = (const float*)d_in[9];
    const float* gru_b_ih = (const float*)d_in[10];
    const float* gru_b_hh = (const float*)d_in[11];
    const float* lin1_w   = (const float*)d_in[12];
    const float* lin1_b   = (const float*)d_in[13];
    const float* lin2_w   = (const float*)d_in[14];
    const int*   ei       = (const int*)d_in[15];
    const int*   batch    = (const int*)d_in[16];
    float* out = (float*)d_out;

    char* p = (char*)d_ws;
    float*  h       = (float*)p;            p += (size_t)N_NODES * DIM * 4;
    float*  out1A   = (float*)p;            p += (size_t)N_NODES * DNN * 4;
    float*  out1B   = (float*)p;            p += (size_t)N_NODES * DNN * 4;
    float4* csr_ea  = (float4*)p;           p += (size_t)N_EDGES * 16;
    __bf16* Wb      = (__bf16*)p;           p += (size_t)WB_SZ * 2;
    __bf16* B2b     = (__bf16*)p;           p += 1536 * 2;
    __bf16* w1b     = (__bf16*)p;           p += 1024 * 2;
    int*    cnt     = (int*)p;              p += (size_t)N_NODES * 4;
    float*  inv_cnt = (float*)p;            p += (size_t)N_NODES * 4;
    int*    row_ptr = (int*)p;              p += (size_t)(N_NODES + 16) * 4;
    int*    cursor  = (int*)p;              p += (size_t)N_NODES * 4;
    int*    excl    = (int*)p;              p += (size_t)N_NODES * 4;
    int*    bsum    = (int*)p;              p += 512 * 4;
    int*    boff    = (int*)p;              p += 512 * 4;
    int*    csr_src = (int*)p;              p += (size_t)N_EDGES * 4;

    hipMemsetAsync(d_out, 0, (size_t)NG * 4, stream);
    hipMemsetAsync(cnt, 0, (size_t)N_NODES * 4, stream);
    k_prep<<<330, 256, 0, stream>>>(gru_w_ih, gru_w_hh, root_w, lin1_w, gru_b_ih, gru_b_hh,
                                    nn1_w, nn1_b, Wb, B2b, w1b);
    k_degree<<<N_EDGES / 256, 256, 0, stream>>>(ei, cnt);
    k_scanA<<<N_NODES / 256, 256, 0, stream>>>(cnt, excl, bsum);
    k_scanB<<<1, 256, 0, stream>>>(bsum, boff);
    k_scanC<<<N_NODES / 256, 256, 0, stream>>>(excl, boff, row_ptr, cursor);
    k_scatter<<<N_EDGES / 256, 256, 0, stream>>>(ei, edge_attr, cursor, csr_src, csr_ea);
    k_invcnt<<<N_NODES / 256, 256, 0, stream>>>(cnt, inv_cnt);
    k_init<<<N_NODES / 16, 256, 0, stream>>>(x, lin0_w, lin0_b, h);
    k_lin1<<<N_NODES / 64, 256, 0, stream>>>(h, lin1_w, lin1_b, out1A);

    for (int it = 0; it < N_ITERS; ++it) {
        int j = it >> 1;   // GRU index (NL2 = 2)
        const float* o_in = (it & 1) ? out1B : out1A;
        float*       o_out= (it & 1) ? out1A : out1B;
        k_node<<<N_NODES / 128, 512, 0, stream>>>(o_in, o_out, csr_src, csr_ea, row_ptr, inv_cnt,
                                                  h, Wb + (size_t)j * 40 * 512, B2b, w1b,
                                                  conv_b, gru_b_ih + (size_t)j * 192, lin1_b);
    }
    k_final<<<N_NODES / 4, 256, 0, stream>>>(h, lin2_w, batch, out);
}

// Round 16
// 454.731 us; speedup vs baseline: 4.7977x; 1.0909x over previous
//
#include <hip/hip_runtime.h>
#include <hip/hip_bf16.h>

#define N_NODES 131072
#define N_EDGES 524288
#define F_IN 16
#define DIM 64
#define DNN 16
#define BK 4
#define NG 8192
#define N_ITERS 8   // NL1*NL2

typedef __bf16 bf16x8 __attribute__((ext_vector_type(8)));
typedef __bf16 bf16x4 __attribute__((ext_vector_type(4)));
typedef float f32x4 __attribute__((ext_vector_type(4)));

#define FMA4(A_, S_, W_) { (A_).x = fmaf((S_), (W_).x, (A_).x); (A_).y = fmaf((S_), (W_).y, (A_).y); \
                           (A_).z = fmaf((S_), (W_).z, (A_).z); (A_).w = fmaf((S_), (W_).w, (A_).w); }

// ---------------- degree (int) ----------------
__global__ __launch_bounds__(256) void k_degree(const int* __restrict__ ei, int* __restrict__ cnt) {
    int e = blockIdx.x * 256 + threadIdx.x;
    atomicAdd(&cnt[ei[N_EDGES + e]], 1);
}

__global__ __launch_bounds__(256) void k_invcnt(const int* __restrict__ cnt, float* __restrict__ inv) {
    int i = blockIdx.x * 256 + threadIdx.x;
    inv[i] = 1.0f / (float)max(cnt[i], 1);
}

// ---------------- CSR scan ----------------
__global__ __launch_bounds__(256) void k_scanA(const int* __restrict__ cnt, int* __restrict__ excl,
                                               int* __restrict__ bsum) {
    __shared__ int a[256], b[256];
    int t = threadIdx.x, gid = blockIdx.x * 256 + t;
    int c = cnt[gid];
    a[t] = c; __syncthreads();
    int *s = a, *d = b;
#pragma unroll
    for (int off = 1; off < 256; off <<= 1) {
        d[t] = s[t] + (t >= off ? s[t - off] : 0);
        __syncthreads();
        int* tmp = s; s = d; d = tmp;
    }
    excl[gid] = s[t] - c;
    if (t == 255) bsum[blockIdx.x] = s[255];
}

__global__ __launch_bounds__(256) void k_scanB(const int* __restrict__ bsum, int* __restrict__ boff) {
    __shared__ int a[512], b[512];
    int t = threadIdx.x;
    a[t] = bsum[t]; a[t + 256] = bsum[t + 256];
    __syncthreads();
    int *s = a, *d = b;
#pragma unroll
    for (int off = 1; off < 512; off <<= 1) {
        d[t] = s[t] + (t >= off ? s[t - off] : 0);
        int i2 = t + 256;
        d[i2] = s[i2] + (i2 >= off ? s[i2 - off] : 0);
        __syncthreads();
        int* tmp = s; s = d; d = tmp;
    }
    boff[t] = t ? s[t - 1] : 0;
    boff[t + 256] = s[t + 255];
}

__global__ __launch_bounds__(256) void k_scanC(const int* __restrict__ excl, const int* __restrict__ boff,
                                               int* __restrict__ row_ptr, int* __restrict__ cursor) {
    int gid = blockIdx.x * 256 + threadIdx.x;
    int v = excl[gid] + boff[gid >> 8];
    row_ptr[gid] = v;
    cursor[gid] = v;
    if (gid == 0) row_ptr[N_NODES] = N_EDGES;
}

__global__ __launch_bounds__(256) void k_scatter(const int* __restrict__ ei, const float* __restrict__ ea,
                                                 int* __restrict__ cursor, int* __restrict__ csr_src,
                                                 float4* __restrict__ csr_ea) {
    int e = blockIdx.x * 256 + threadIdx.x;
    int dst = ei[N_EDGES + e];
    int pos = atomicAdd(&cursor[dst], 1);
    csr_src[pos] = ei[e];
    csr_ea[pos] = ((const float4*)ea)[e];
}

// ---------------- prep: bf16 B-fragment weight tiles ----------------
// Wb: gates tiles. B2b: o2 tiles K=96 (rows 0..15 root_w, 16..31 nn1b, 32..95 nn1w).
#define WB_SZ (4 * 40 * 512)
__global__ __launch_bounds__(256) void k_prep(const float* __restrict__ wih, const float* __restrict__ whh,
                                              const float* __restrict__ rw, const float* __restrict__ w1,
                                              const float* __restrict__ bih, const float* __restrict__ bhh,
                                              const float* __restrict__ nn1w, const float* __restrict__ nn1b,
                                              __bf16* __restrict__ Wb, __bf16* __restrict__ B2b,
                                              __bf16* __restrict__ w1b) {
    int idx = blockIdx.x * 256 + threadIdx.x;
    if (idx < WB_SZ) {
        int j = idx / 20480, r = idx % 20480;
        int t = r >> 9, e = r & 511;
        int jj = e & 7, c16 = (e >> 3) & 15, kq = e >> 7;
        int ct, kk; bool nih = false;
        if (t < 36) { ct = t / 3; kk = t % 3; } else { ct = 8 + (t - 36); kk = 0; nih = true; }
        int k = kk * 32 + kq * 8 + jj;
        int c = ct * 16 + c16;
        bool ngate = ct >= 8;
        float v = 0.f;
        if (nih) {
            if (k < 16) v = wih[((size_t)j * 192 + c) * 16 + k];
        } else {
            if (k < 16) v = ngate ? 0.f : wih[((size_t)j * 192 + c) * 16 + k];
            else if (k < 80) v = whh[((size_t)j * 192 + c) * 64 + (k - 16)];
            else if (k == 80) v = ngate ? bhh[j * 192 + c] : (bih[j * 192 + c] + bhh[j * 192 + c]);
        }
        Wb[idx] = (__bf16)v;
    } else if (idx < WB_SZ + 1536) {
        int e = idx - WB_SZ;
        int t = e >> 9, ee = e & 511;
        int jj = ee & 7, c16 = (ee >> 3) & 15, kq = ee >> 7;
        int krow = t * 32 + kq * 8 + jj;
        float v;
        if (krow < 16) v = rw[krow * 16 + c16];
        else {
            int i = (krow - 16) >> 4, kk = (krow - 16) & 15;
            v = (i == 0) ? nn1b[kk * 16 + c16] : nn1w[(i - 1) * 256 + kk * 16 + c16];
        }
        B2b[e] = (__bf16)v;
    } else if (idx < WB_SZ + 1536 + 1024) {
        int e = idx - (WB_SZ + 1536);
        int t2 = e >> 9, ee = e & 511;
        int jj = ee & 7, c16 = (ee >> 3) & 15, kq = ee >> 7;
        int k = t2 * 32 + kq * 8 + jj;
        w1b[e] = (__bf16)w1[k * 16 + c16];
    }
}

// ---------------- init: h = relu(x @ lin0_w + lin0_b) ----------------
__global__ __launch_bounds__(256) void k_init(const float* __restrict__ x, const float* __restrict__ w,
                                              const float* __restrict__ b, float* __restrict__ h) {
    __shared__ float s_w[F_IN * DIM];
    int tid = threadIdx.x;
    for (int i = tid; i < F_IN * DIM; i += 256) s_w[i] = w[i];
    int node = blockIdx.x * 16 + (tid >> 4);
    int c4 = tid & 15;
    const float4* xp = (const float4*)(x + (size_t)node * F_IN);
    float4 x0 = xp[0], x1 = xp[1], x2 = xp[2], x3 = xp[3];
    float xa[16] = {x0.x, x0.y, x0.z, x0.w, x1.x, x1.y, x1.z, x1.w,
                    x2.x, x2.y, x2.z, x2.w, x3.x, x3.y, x3.z, x3.w};
    __syncthreads();
    float4 acc = ((const float4*)b)[c4];
    const float4* w4 = (const float4*)s_w;
#pragma unroll
    for (int k = 0; k < 16; ++k) {
        float4 wv = w4[k * 16 + c4];
        FMA4(acc, xa[k], wv);
    }
    acc.x = fmaxf(acc.x, 0.f); acc.y = fmaxf(acc.y, 0.f);
    acc.z = fmaxf(acc.z, 0.f); acc.w = fmaxf(acc.w, 0.f);
    *(float4*)(h + (size_t)node * DIM + c4 * 4) = acc;
}

// ---------------- out1 = h @ lin1_w + lin1_b (once, pre-loop; bf16 out) ----------------
__global__ __launch_bounds__(256) void k_lin1(const float* __restrict__ h, const float* __restrict__ w,
                                              const float* __restrict__ b, __bf16* __restrict__ out1) {
    __shared__ float s_h[64 * 68];
    int tid = threadIdx.x;
    int nb = blockIdx.x * 64;
    const float4* hp = (const float4*)(h + (size_t)nb * 64);
    for (int i = tid; i < 64 * 16; i += 256) {
        int n = i >> 4, q4 = i & 15;
        float4 v = hp[i];
        *(float4*)&s_h[n * 68 + q4 * 4] = v;
    }
    int ct = tid & 15;
    float wcol[64];
#pragma unroll
    for (int q = 0; q < 64; ++q) wcol[q] = w[q * 16 + ct];
    float bias = b[ct];
    __syncthreads();
    int ng = tid >> 4;
#pragma unroll
    for (int rep = 0; rep < 4; ++rep) {
        int nl = ng + 16 * rep;
        float acc = bias;
#pragma unroll
        for (int q4 = 0; q4 < 16; ++q4) {
            float4 hv = *(const float4*)&s_h[nl * 68 + q4 * 4];
            acc = fmaf(hv.x, wcol[4 * q4 + 0], acc);
            acc = fmaf(hv.y, wcol[4 * q4 + 1], acc);
            acc = fmaf(hv.z, wcol[4 * q4 + 2], acc);
            acc = fmaf(hv.w, wcol[4 * q4 + 3], acc);
        }
        out1[(size_t)(nb + nl) * 16 + ct] = (__bf16)acc;
    }
}

// ---------------- node v10: bf16 out1 + pipelined gather + MFMA GRU ----------------
// vs R15 v9: (1) out1 bf16 (gather set 4.2MB -> L2-resident; half traffic);
// (2) gather prefetches next round's csr_src (+4 VGPR) so the 2-level
// csr->out1 chain overlaps (round = max not sum of latencies);
// (3) epilogue hold read from s_X bf16 (same-wave DS order) - no 2nd h read.
__attribute__((amdgpu_waves_per_eu(2, 4)))
__global__ __launch_bounds__(512) void k_node(
    const __bf16* __restrict__ out1_in, __bf16* __restrict__ out1_out,
    const int* __restrict__ csr_src, const float4* __restrict__ csr_ea,
    const int* __restrict__ row_ptr, const float* __restrict__ inv_cnt,
    float* __restrict__ h, const __bf16* __restrict__ Wb, const __bf16* __restrict__ B2b,
    const __bf16* __restrict__ w1b, const float* __restrict__ conv_b,
    const float* __restrict__ bih, const float* __restrict__ lin1_b)
{
    __shared__ __align__(16) __bf16 s_X[128 * 104];  // 26624 B
    __shared__ __align__(16) __bf16 s_W[40 * 512];   // 40960 B
    __shared__ __align__(16) __bf16 s_B2[3 * 512];   //  3072 B
    __shared__ __align__(16) __bf16 s_w1[1024];      //  2048 B  (total 72704)
    int tid = threadIdx.x;
    int nb = blockIdx.x * 128;
    int lane = tid & 63, w = tid >> 6;               // w = 0..7
    int c16 = lane & 15, lq = lane >> 4;
    int nwb = nb + w * 16;
    int xrow = w * 16;

    // cooperative staging of weight tiles (512 threads)
    {
        const float4* src = (const float4*)Wb;
        float4* dst = (float4*)s_W;
#pragma unroll
        for (int i = 0; i < 5; ++i) dst[tid + 512 * i] = src[tid + 512 * i];
        if (tid < 192) ((float4*)s_B2)[tid] = ((const float4*)B2b)[tid];
        else if (tid < 320) ((float4*)s_w1)[tid - 192] = ((const float4*)w1b)[tid - 192];
    }
    // own out1 row -> X2[.][0..15] (straight bf16 copy)
    {
        int n = lane >> 2, k4 = lane & 3;
        bf16x4 v = *(const bf16x4*)&out1_in[(size_t)(nwb + n) * 16 + k4 * 4];
        *(bf16x4*)&s_X[(xrow + n) * 104 + k4 * 4] = v;
    }

    // gather: 32 groups x 4 interleaved chains; csr_src prefetched 1 round ahead
    {
        int g = tid >> 4, k = tid & 15;              // g = 0..31
        int ec[4], ee[4], vs[4];
        float S0[4] = {0.f,0.f,0.f,0.f}, S1[4] = {0.f,0.f,0.f,0.f}, S2[4] = {0.f,0.f,0.f,0.f},
              S3[4] = {0.f,0.f,0.f,0.f}, S4[4] = {0.f,0.f,0.f,0.f};
#pragma unroll
        for (int r = 0; r < 4; ++r) {
            int n = nb + g + 32 * r;
            ec[r] = row_ptr[n]; ee[r] = row_ptr[n + 1];
            vs[r] = csr_src[min(ec[r], N_EDGES - 1)];   // round-0 src prefetch
        }
        bool more = (ec[0] < ee[0]) | (ec[1] < ee[1]) | (ec[2] < ee[2]) | (ec[3] < ee[3]);
        while (more) {
            float4 av[4]; float xv[4]; bool act[4]; int vs2[4];
#pragma unroll
            for (int r = 0; r < 4; ++r) {
                act[r] = ec[r] < ee[r];
                int e = min(ec[r], N_EDGES - 1);
                av[r] = csr_ea[e];                          // current round ea
                int e2 = min(ec[r] + (act[r] ? 1 : 0), N_EDGES - 1);
                vs2[r] = csr_src[e2];                       // next round src
            }
#pragma unroll
            for (int r = 0; r < 4; ++r)
                xv[r] = (float)out1_in[(size_t)(vs[r] & 0xFFFFF) * 16 + k];
#pragma unroll
            for (int r = 0; r < 4; ++r) {
                if (act[r]) {
                    S0[r] += xv[r];
                    S1[r] = fmaf(av[r].x, xv[r], S1[r]);
                    S2[r] = fmaf(av[r].y, xv[r], S2[r]);
                    S3[r] = fmaf(av[r].z, xv[r], S3[r]);
                    S4[r] = fmaf(av[r].w, xv[r], S4[r]);
                    ec[r]++;
                }
                vs[r] = vs2[r];
            }
            more = (ec[0] < ee[0]) | (ec[1] < ee[1]) | (ec[2] < ee[2]) | (ec[3] < ee[3]);
        }
#pragma unroll
        for (int r = 0; r < 4; ++r) {
            int nl = g + 32 * r;
            float inv = inv_cnt[nb + nl];
            __bf16* p = &s_X[nl * 104];
            p[16 + k] = (__bf16)(S0[r] * inv);
            p[32 + k] = (__bf16)(S1[r] * inv);
            p[48 + k] = (__bf16)(S2[r] * inv);
            p[64 + k] = (__bf16)(S3[r] * inv);
            p[80 + k] = (__bf16)(S4[r] * inv);
        }
    }
    __syncthreads();

    // phase 2: o2 = X2 @ B2 + conv_b (K=96)
    float cb = conv_b[c16];
    f32x4 co2 = (f32x4){cb, cb, cb, cb};
#pragma unroll
    for (int kk = 0; kk < 3; ++kk) {
        bf16x8 a = *(const bf16x8*)&s_X[(xrow + c16) * 104 + kk * 32 + lq * 8];
        bf16x8 b = *(const bf16x8*)&s_B2[kk * 512 + lane * 8];
        co2 = __builtin_amdgcn_mfma_f32_16x16x32_bf16(a, b, co2, 0, 0, 0);
    }

    // phase 3a: rebuild X = [o2(16) | h(64) | 1 | 0..] (wave-own rows, same-wave DS order)
#pragma unroll
    for (int jr = 0; jr < 4; ++jr)
        s_X[(xrow + 4 * lq + jr) * 104 + c16] = (__bf16)co2[jr];
    {
        const float4* hsrc = (const float4*)(h + (size_t)nwb * 64);
#pragma unroll
        for (int ii = 0; ii < 4; ++ii) {
            int idx = lane + 64 * ii;
            int n = idx >> 4, d4 = idx & 15;
            float4 v = hsrc[idx];
            __bf16* p = &s_X[(xrow + n) * 104 + 16 + d4 * 4];
            p[0] = (__bf16)v.x; p[1] = (__bf16)v.y; p[2] = (__bf16)v.z; p[3] = (__bf16)v.w;
        }
    }
    {
        int n = lane >> 2, c0 = 80 + (lane & 3) * 4;
#pragma unroll
        for (int q = 0; q < 4; ++q)
            s_X[(xrow + n) * 104 + c0 + q] = (c0 + q == 80) ? (__bf16)1.0f : (__bf16)0.0f;
    }

    // phase 3b: gates GEMM
    f32x4 acc[12], ani4[4];
#pragma unroll
    for (int i = 0; i < 12; ++i) acc[i] = (f32x4){0.f, 0.f, 0.f, 0.f};
#pragma unroll
    for (int i = 0; i < 4; ++i) ani4[i] = (f32x4){0.f, 0.f, 0.f, 0.f};
    bf16x8 af[3];
#pragma unroll
    for (int kk = 0; kk < 3; ++kk)
        af[kk] = *(const bf16x8*)&s_X[(xrow + c16) * 104 + kk * 32 + lq * 8];
#pragma unroll
    for (int ct = 0; ct < 12; ++ct) {
#pragma unroll
        for (int kk = 0; kk < 3; ++kk) {
            bf16x8 bf = *(const bf16x8*)&s_W[(ct * 3 + kk) * 512 + lane * 8];
            acc[ct] = __builtin_amdgcn_mfma_f32_16x16x32_bf16(af[kk], bf, acc[ct], 0, 0, 0);
        }
    }
#pragma unroll
    for (int ct8 = 0; ct8 < 4; ++ct8) {
        bf16x8 bf = *(const bf16x8*)&s_W[(36 + ct8) * 512 + lane * 8];
        ani4[ct8] = __builtin_amdgcn_mfma_f32_16x16x32_bf16(af[0], bf, ani4[ct8], 0, 0, 0);
    }

    // GRU epilogue (hold from s_X bf16 — same value staged above, no 2nd h read)
    float hn[4][4];
#pragma unroll
    for (int ct = 0; ct < 4; ++ct) {
        float bni = bih[128 + ct * 16 + c16];
#pragma unroll
        for (int jr = 0; jr < 4; ++jr) {
            int node = nwb + 4 * lq + jr;
            float hold = (float)s_X[(xrow + 4 * lq + jr) * 104 + 16 + ct * 16 + c16];
            float rr = 1.f / (1.f + __expf(-acc[ct][jr]));
            float zz = 1.f / (1.f + __expf(-acc[4 + ct][jr]));
            float xx = fmaf(rr, acc[8 + ct][jr], ani4[ct][jr] + bni);
            float ax = fabsf(xx);
            float ee = __expf(-2.f * ax);
            float ncv = __builtin_copysignf((1.f - ee) / (1.f + ee), xx);
            float hv = fmaf(zz, hold - ncv, ncv);
            hn[ct][jr] = hv;
            h[(size_t)node * 64 + ct * 16 + c16] = hv;
        }
    }
#pragma unroll
    for (int ct = 0; ct < 4; ++ct)
#pragma unroll
        for (int jr = 0; jr < 4; ++jr)
            s_X[(xrow + 4 * lq + jr) * 104 + 16 + ct * 16 + c16] = (__bf16)hn[ct][jr];

    // fused lin1 -> out1_out (bf16)
    f32x4 o1acc = (f32x4){0.f, 0.f, 0.f, 0.f};
#pragma unroll
    for (int kk = 0; kk < 2; ++kk) {
        bf16x8 a = *(const bf16x8*)&s_X[(xrow + c16) * 104 + 16 + kk * 32 + lq * 8];
        bf16x8 b = *(const bf16x8*)&s_w1[kk * 512 + lane * 8];
        o1acc = __builtin_amdgcn_mfma_f32_16x16x32_bf16(a, b, o1acc, 0, 0, 0);
    }
    float lb = lin1_b[c16];
#pragma unroll
    for (int jr = 0; jr < 4; ++jr) {
        int node = nwb + 4 * lq + jr;
        out1_out[(size_t)node * 16 + c16] = (__bf16)(o1acc[jr] + lb);
    }
}

// ---------------- final ----------------
__global__ __launch_bounds__(256) void k_final(const float* __restrict__ h, const float* __restrict__ w2,
                                               const int* __restrict__ batch, float* __restrict__ out) {
    int i = blockIdx.x * 4 + (threadIdx.x >> 6);
    int lane = threadIdx.x & 63;
    float v = h[(size_t)i * DIM + lane] * w2[lane];
#pragma unroll
    for (int off = 32; off > 0; off >>= 1) v += __shfl_down(v, off, 64);
    if (lane == 0) atomicAdd(&out[batch[i]], v);
}

extern "C" void kernel_launch(void* const* d_in, const int* in_sizes, int n_in,
                              void* d_out, int out_size, void* d_ws, size_t ws_size,
                              hipStream_t stream) {
    const float* x        = (const float*)d_in[0];
    const float* edge_attr= (const float*)d_in[1];
    const float* lin0_w   = (const float*)d_in[2];
    const float* lin0_b   = (const float*)d_in[3];
    const float* nn1_w    = (const float*)d_in[4];
    const float* nn1_b    = (const float*)d_in[5];
    const float* root_w   = (const float*)d_in[6];
    const float* conv_b   = (const float*)d_in[7];
    const float* gru_w_ih = (const float*)d_in[8];
    const float* gru_w_hh = (const float*)d_in[9];
    const float* gru_b_ih = (const float*)d_in[10];
    const float* gru_b_hh = (const float*)d_in[11];
    const float* lin1_w   = (const float*)d_in[12];
    const float* lin1_b   = (const float*)d_in[13];
    const float* lin2_w   = (const float*)d_in[14];
    const int*   ei       = (const int*)d_in[15];
    const int*   batch    = (const int*)d_in[16];
    float* out = (float*)d_out;

    char* p = (char*)d_ws;
    float*  h       = (float*)p;            p += (size_t)N_NODES * DIM * 4;
    __bf16* out1A   = (__bf16*)p;           p += (size_t)N_NODES * DNN * 2;
    __bf16* out1B   = (__bf16*)p;           p += (size_t)N_NODES * DNN * 2;
    float4* csr_ea  = (float4*)p;           p += (size_t)N_EDGES * 16;
    __bf16* Wb      = (__bf16*)p;           p += (size_t)WB_SZ * 2;
    __bf16* B2b     = (__bf16*)p;           p += 1536 * 2;
    __bf16* w1b     = (__bf16*)p;           p += 1024 * 2;
    int*    cnt     = (int*)p;              p += (size_t)N_NODES * 4;
    float*  inv_cnt = (float*)p;            p += (size_t)N_NODES * 4;
    int*    row_ptr = (int*)p;              p += (size_t)(N_NODES + 16) * 4;
    int*    cursor  = (int*)p;              p += (size_t)N_NODES * 4;
    int*    excl    = (int*)p;              p += (size_t)N_NODES * 4;
    int*    bsum    = (int*)p;              p += 512 * 4;
    int*    boff    = (int*)p;              p += 512 * 4;
    int*    csr_src = (int*)p;              p += (size_t)N_EDGES * 4;

    hipMemsetAsync(d_out, 0, (size_t)NG * 4, stream);
    hipMemsetAsync(cnt, 0, (size_t)N_NODES * 4, stream);
    k_prep<<<330, 256, 0, stream>>>(gru_w_ih, gru_w_hh, root_w, lin1_w, gru_b_ih, gru_b_hh,
                                    nn1_w, nn1_b, Wb, B2b, w1b);
    k_degree<<<N_EDGES / 256, 256, 0, stream>>>(ei, cnt);
    k_scanA<<<N_NODES / 256, 256, 0, stream>>>(cnt, excl, bsum);
    k_scanB<<<1, 256, 0, stream>>>(bsum, boff);
    k_scanC<<<N_NODES / 256, 256, 0, stream>>>(excl, boff, row_ptr, cursor);
    k_scatter<<<N_EDGES / 256, 256, 0, stream>>>(ei, edge_attr, cursor, csr_src, csr_ea);
    k_invcnt<<<N_NODES / 256, 256, 0, stream>>>(cnt, inv_cnt);
    k_init<<<N_NODES / 16, 256, 0, stream>>>(x, lin0_w, lin0_b, h);
    k_lin1<<<N_NODES / 64, 256, 0, stream>>>(h, lin1_w, lin1_b, out1A);

    for (int it = 0; it < N_ITERS; ++it) {
        int j = it >> 1;   // GRU index (NL2 = 2)
        const __bf16* o_in = (it & 1) ? out1B : out1A;
        __bf16*       o_out= (it & 1) ? out1A : out1B;
        k_node<<<N_NODES / 128, 512, 0, stream>>>(o_in, o_out, csr_src, csr_ea, row_ptr, inv_cnt,
                                                  h, Wb + (size_t)j * 40 * 512, B2b, w1b,
                                                  conv_b, gru_b_ih + (size_t)j * 192, lin1_b);
    }
    k_final<<<N_NODES / 4, 256, 0, stream>>>(h, lin2_w, batch, out);
}

// Round 17
// 408.101 us; speedup vs baseline: 5.3459x; 1.1143x over previous
//
#include <hip/hip_runtime.h>
#include <hip/hip_bf16.h>

#define N_NODES 131072
#define N_EDGES 524288
#define F_IN 16
#define DIM 64
#define DNN 16
#define BK 4
#define NG 8192
#define N_ITERS 8   // NL1*NL2

typedef __bf16 bf16x8 __attribute__((ext_vector_type(8)));
typedef __bf16 bf16x4 __attribute__((ext_vector_type(4)));
typedef float f32x4 __attribute__((ext_vector_type(4)));

#define FMA4(A_, S_, W_) { (A_).x = fmaf((S_), (W_).x, (A_).x); (A_).y = fmaf((S_), (W_).y, (A_).y); \
                           (A_).z = fmaf((S_), (W_).z, (A_).z); (A_).w = fmaf((S_), (W_).w, (A_).w); }

// ---------------- degree (int) ----------------
__global__ __launch_bounds__(256) void k_degree(const int* __restrict__ ei, int* __restrict__ cnt) {
    int e = blockIdx.x * 256 + threadIdx.x;
    atomicAdd(&cnt[ei[N_EDGES + e]], 1);
}

__global__ __launch_bounds__(256) void k_invcnt(const int* __restrict__ cnt, float* __restrict__ inv) {
    int i = blockIdx.x * 256 + threadIdx.x;
    inv[i] = 1.0f / (float)max(cnt[i], 1);
}

// ---------------- CSR scan ----------------
__global__ __launch_bounds__(256) void k_scanA(const int* __restrict__ cnt, int* __restrict__ excl,
                                               int* __restrict__ bsum) {
    __shared__ int a[256], b[256];
    int t = threadIdx.x, gid = blockIdx.x * 256 + t;
    int c = cnt[gid];
    a[t] = c; __syncthreads();
    int *s = a, *d = b;
#pragma unroll
    for (int off = 1; off < 256; off <<= 1) {
        d[t] = s[t] + (t >= off ? s[t - off] : 0);
        __syncthreads();
        int* tmp = s; s = d; d = tmp;
    }
    excl[gid] = s[t] - c;
    if (t == 255) bsum[blockIdx.x] = s[255];
}

__global__ __launch_bounds__(256) void k_scanB(const int* __restrict__ bsum, int* __restrict__ boff) {
    __shared__ int a[512], b[512];
    int t = threadIdx.x;
    a[t] = bsum[t]; a[t + 256] = bsum[t + 256];
    __syncthreads();
    int *s = a, *d = b;
#pragma unroll
    for (int off = 1; off < 512; off <<= 1) {
        d[t] = s[t] + (t >= off ? s[t - off] : 0);
        int i2 = t + 256;
        d[i2] = s[i2] + (i2 >= off ? s[i2 - off] : 0);
        __syncthreads();
        int* tmp = s; s = d; d = tmp;
    }
    boff[t] = t ? s[t - 1] : 0;
    boff[t + 256] = s[t + 255];
}

__global__ __launch_bounds__(256) void k_scanC(const int* __restrict__ excl, const int* __restrict__ boff,
                                               int* __restrict__ row_ptr, int* __restrict__ cursor) {
    int gid = blockIdx.x * 256 + threadIdx.x;
    int v = excl[gid] + boff[gid >> 8];
    row_ptr[gid] = v;
    cursor[gid] = v;
    if (gid == 0) row_ptr[N_NODES] = N_EDGES;
}

__global__ __launch_bounds__(256) void k_scatter(const int* __restrict__ ei, const float* __restrict__ ea,
                                                 int* __restrict__ cursor, int* __restrict__ csr_src,
                                                 float4* __restrict__ csr_ea) {
    int e = blockIdx.x * 256 + threadIdx.x;
    int dst = ei[N_EDGES + e];
    int pos = atomicAdd(&cursor[dst], 1);
    csr_src[pos] = ei[e];
    csr_ea[pos] = ((const float4*)ea)[e];
}

// ---------------- prep: bf16 B-fragment weight tiles ----------------
#define WB_SZ (4 * 40 * 512)
__global__ __launch_bounds__(256) void k_prep(const float* __restrict__ wih, const float* __restrict__ whh,
                                              const float* __restrict__ rw, const float* __restrict__ w1,
                                              const float* __restrict__ bih, const float* __restrict__ bhh,
                                              const float* __restrict__ nn1w, const float* __restrict__ nn1b,
                                              __bf16* __restrict__ Wb, __bf16* __restrict__ B2b,
                                              __bf16* __restrict__ w1b) {
    int idx = blockIdx.x * 256 + threadIdx.x;
    if (idx < WB_SZ) {
        int j = idx / 20480, r = idx % 20480;
        int t = r >> 9, e = r & 511;
        int jj = e & 7, c16 = (e >> 3) & 15, kq = e >> 7;
        int ct, kk; bool nih = false;
        if (t < 36) { ct = t / 3; kk = t % 3; } else { ct = 8 + (t - 36); kk = 0; nih = true; }
        int k = kk * 32 + kq * 8 + jj;
        int c = ct * 16 + c16;
        bool ngate = ct >= 8;
        float v = 0.f;
        if (nih) {
            if (k < 16) v = wih[((size_t)j * 192 + c) * 16 + k];
        } else {
            if (k < 16) v = ngate ? 0.f : wih[((size_t)j * 192 + c) * 16 + k];
            else if (k < 80) v = whh[((size_t)j * 192 + c) * 64 + (k - 16)];
            else if (k == 80) v = ngate ? bhh[j * 192 + c] : (bih[j * 192 + c] + bhh[j * 192 + c]);
        }
        Wb[idx] = (__bf16)v;
    } else if (idx < WB_SZ + 1536) {
        int e = idx - WB_SZ;
        int t = e >> 9, ee = e & 511;
        int jj = ee & 7, c16 = (ee >> 3) & 15, kq = ee >> 7;
        int krow = t * 32 + kq * 8 + jj;
        float v;
        if (krow < 16) v = rw[krow * 16 + c16];
        else {
            int i = (krow - 16) >> 4, kk = (krow - 16) & 15;
            v = (i == 0) ? nn1b[kk * 16 + c16] : nn1w[(i - 1) * 256 + kk * 16 + c16];
        }
        B2b[e] = (__bf16)v;
    } else if (idx < WB_SZ + 1536 + 1024) {
        int e = idx - (WB_SZ + 1536);
        int t2 = e >> 9, ee = e & 511;
        int jj = ee & 7, c16 = (ee >> 3) & 15, kq = ee >> 7;
        int k = t2 * 32 + kq * 8 + jj;
        w1b[e] = (__bf16)w1[k * 16 + c16];
    }
}

// ---------------- init: h = relu(x @ lin0_w + lin0_b) -> bf16 ----------------
__global__ __launch_bounds__(256) void k_init(const float* __restrict__ x, const float* __restrict__ w,
                                              const float* __restrict__ b, __bf16* __restrict__ h) {
    __shared__ float s_w[F_IN * DIM];
    int tid = threadIdx.x;
    for (int i = tid; i < F_IN * DIM; i += 256) s_w[i] = w[i];
    int node = blockIdx.x * 16 + (tid >> 4);
    int c4 = tid & 15;
    const float4* xp = (const float4*)(x + (size_t)node * F_IN);
    float4 x0 = xp[0], x1 = xp[1], x2 = xp[2], x3 = xp[3];
    float xa[16] = {x0.x, x0.y, x0.z, x0.w, x1.x, x1.y, x1.z, x1.w,
                    x2.x, x2.y, x2.z, x2.w, x3.x, x3.y, x3.z, x3.w};
    __syncthreads();
    float4 acc = ((const float4*)b)[c4];
    const float4* w4 = (const float4*)s_w;
#pragma unroll
    for (int k = 0; k < 16; ++k) {
        float4 wv = w4[k * 16 + c4];
        FMA4(acc, xa[k], wv);
    }
    bf16x4 hv;
    hv[0] = (__bf16)fmaxf(acc.x, 0.f); hv[1] = (__bf16)fmaxf(acc.y, 0.f);
    hv[2] = (__bf16)fmaxf(acc.z, 0.f); hv[3] = (__bf16)fmaxf(acc.w, 0.f);
    *(bf16x4*)&h[(size_t)node * DIM + c4 * 4] = hv;
}

// ---------------- out1 = h @ lin1_w + lin1_b (once, pre-loop; bf16 in/out) ----------------
__global__ __launch_bounds__(256) void k_lin1(const __bf16* __restrict__ h, const float* __restrict__ w,
                                              const float* __restrict__ b, __bf16* __restrict__ out1) {
    __shared__ float s_h[64 * 68];
    int tid = threadIdx.x;
    int nb = blockIdx.x * 64;
    for (int i = tid; i < 64 * 16; i += 256) {
        int n = i >> 4, q4 = i & 15;
        bf16x4 v = *(const bf16x4*)&h[(size_t)(nb + n) * 64 + q4 * 4];
        float* d = &s_h[n * 68 + q4 * 4];
        d[0] = (float)v[0]; d[1] = (float)v[1]; d[2] = (float)v[2]; d[3] = (float)v[3];
    }
    int ct = tid & 15;
    float wcol[64];
#pragma unroll
    for (int q = 0; q < 64; ++q) wcol[q] = w[q * 16 + ct];
    float bias = b[ct];
    __syncthreads();
    int ng = tid >> 4;
#pragma unroll
    for (int rep = 0; rep < 4; ++rep) {
        int nl = ng + 16 * rep;
        float acc = bias;
#pragma unroll
        for (int q4 = 0; q4 < 16; ++q4) {
            float4 hv = *(const float4*)&s_h[nl * 68 + q4 * 4];
            acc = fmaf(hv.x, wcol[4 * q4 + 0], acc);
            acc = fmaf(hv.y, wcol[4 * q4 + 1], acc);
            acc = fmaf(hv.z, wcol[4 * q4 + 2], acc);
            acc = fmaf(hv.w, wcol[4 * q4 + 3], acc);
        }
        out1[(size_t)(nb + nl) * 16 + ct] = (__bf16)acc;
    }
}

// ---------------- node v11: bf16 h + pipelined gather + MFMA GRU + fused final ----------------
// vs v10: h stored bf16 (halves h traffic; hold was already bf16 via s_X);
// do_final: on last iter compute y = h_new @ lin2_w in-register (shfl_xor
// reduce over the 16 c16-lanes) + atomicAdd to out[batch]; skip out1 write.
__attribute__((amdgpu_waves_per_eu(2, 4)))
__global__ __launch_bounds__(512) void k_node(
    const __bf16* __restrict__ out1_in, __bf16* __restrict__ out1_out,
    const int* __restrict__ csr_src, const float4* __restrict__ csr_ea,
    const int* __restrict__ row_ptr, const float* __restrict__ inv_cnt,
    __bf16* __restrict__ h, const __bf16* __restrict__ Wb, const __bf16* __restrict__ B2b,
    const __bf16* __restrict__ w1b, const float* __restrict__ conv_b,
    const float* __restrict__ bih, const float* __restrict__ lin1_b,
    const int* __restrict__ batch, const float* __restrict__ lin2_w,
    float* __restrict__ out, int do_final)
{
    __shared__ __align__(16) __bf16 s_X[128 * 104];  // 26624 B
    __shared__ __align__(16) __bf16 s_W[40 * 512];   // 40960 B
    __shared__ __align__(16) __bf16 s_B2[3 * 512];   //  3072 B
    __shared__ __align__(16) __bf16 s_w1[1024];      //  2048 B  (total 72704)
    int tid = threadIdx.x;
    int nb = blockIdx.x * 128;
    int lane = tid & 63, w = tid >> 6;               // w = 0..7
    int c16 = lane & 15, lq = lane >> 4;
    int nwb = nb + w * 16;
    int xrow = w * 16;

    // cooperative staging of weight tiles (512 threads)
    {
        const float4* src = (const float4*)Wb;
        float4* dst = (float4*)s_W;
#pragma unroll
        for (int i = 0; i < 5; ++i) dst[tid + 512 * i] = src[tid + 512 * i];
        if (tid < 192) ((float4*)s_B2)[tid] = ((const float4*)B2b)[tid];
        else if (tid < 320) ((float4*)s_w1)[tid - 192] = ((const float4*)w1b)[tid - 192];
    }
    // own out1 row -> X2[.][0..15]
    {
        int n = lane >> 2, k4 = lane & 3;
        bf16x4 v = *(const bf16x4*)&out1_in[(size_t)(nwb + n) * 16 + k4 * 4];
        *(bf16x4*)&s_X[(xrow + n) * 104 + k4 * 4] = v;
    }

    // gather: 32 groups x 4 interleaved chains; csr_src prefetched 1 round ahead
    {
        int g = tid >> 4, k = tid & 15;              // g = 0..31
        int ec[4], ee[4], vs[4];
        float S0[4] = {0.f,0.f,0.f,0.f}, S1[4] = {0.f,0.f,0.f,0.f}, S2[4] = {0.f,0.f,0.f,0.f},
              S3[4] = {0.f,0.f,0.f,0.f}, S4[4] = {0.f,0.f,0.f,0.f};
#pragma unroll
        for (int r = 0; r < 4; ++r) {
            int n = nb + g + 32 * r;
            ec[r] = row_ptr[n]; ee[r] = row_ptr[n + 1];
            vs[r] = csr_src[min(ec[r], N_EDGES - 1)];
        }
        bool more = (ec[0] < ee[0]) | (ec[1] < ee[1]) | (ec[2] < ee[2]) | (ec[3] < ee[3]);
        while (more) {
            float4 av[4]; float xv[4]; bool act[4]; int vs2[4];
#pragma unroll
            for (int r = 0; r < 4; ++r) {
                act[r] = ec[r] < ee[r];
                int e = min(ec[r], N_EDGES - 1);
                av[r] = csr_ea[e];
                int e2 = min(ec[r] + (act[r] ? 1 : 0), N_EDGES - 1);
                vs2[r] = csr_src[e2];
            }
#pragma unroll
            for (int r = 0; r < 4; ++r)
                xv[r] = (float)out1_in[(size_t)(vs[r] & 0xFFFFF) * 16 + k];
#pragma unroll
            for (int r = 0; r < 4; ++r) {
                if (act[r]) {
                    S0[r] += xv[r];
                    S1[r] = fmaf(av[r].x, xv[r], S1[r]);
                    S2[r] = fmaf(av[r].y, xv[r], S2[r]);
                    S3[r] = fmaf(av[r].z, xv[r], S3[r]);
                    S4[r] = fmaf(av[r].w, xv[r], S4[r]);
                    ec[r]++;
                }
                vs[r] = vs2[r];
            }
            more = (ec[0] < ee[0]) | (ec[1] < ee[1]) | (ec[2] < ee[2]) | (ec[3] < ee[3]);
        }
#pragma unroll
        for (int r = 0; r < 4; ++r) {
            int nl = g + 32 * r;
            float inv = inv_cnt[nb + nl];
            __bf16* p = &s_X[nl * 104];
            p[16 + k] = (__bf16)(S0[r] * inv);
            p[32 + k] = (__bf16)(S1[r] * inv);
            p[48 + k] = (__bf16)(S2[r] * inv);
            p[64 + k] = (__bf16)(S3[r] * inv);
            p[80 + k] = (__bf16)(S4[r] * inv);
        }
    }
    __syncthreads();

    // phase 2: o2 = X2 @ B2 + conv_b (K=96)
    float cb = conv_b[c16];
    f32x4 co2 = (f32x4){cb, cb, cb, cb};
#pragma unroll
    for (int kk = 0; kk < 3; ++kk) {
        bf16x8 a = *(const bf16x8*)&s_X[(xrow + c16) * 104 + kk * 32 + lq * 8];
        bf16x8 b = *(const bf16x8*)&s_B2[kk * 512 + lane * 8];
        co2 = __builtin_amdgcn_mfma_f32_16x16x32_bf16(a, b, co2, 0, 0, 0);
    }

    // phase 3a: rebuild X = [o2(16) | h(64) | 1 | 0..]
#pragma unroll
    for (int jr = 0; jr < 4; ++jr)
        s_X[(xrow + 4 * lq + jr) * 104 + c16] = (__bf16)co2[jr];
    {
        // h is bf16: wave copies its 16 nodes x 64 cols = 128 x bf16x8
        const bf16x8* hsrc = (const bf16x8*)(h + (size_t)nwb * 64);
#pragma unroll
        for (int ii = 0; ii < 2; ++ii) {
            int idx = lane + 64 * ii;
            int n = idx >> 3, d8 = idx & 7;
            bf16x8 v = hsrc[idx];
            *(bf16x8*)&s_X[(xrow + n) * 104 + 16 + d8 * 8] = v;
        }
    }
    {
        int n = lane >> 2, c0 = 80 + (lane & 3) * 4;
#pragma unroll
        for (int q = 0; q < 4; ++q)
            s_X[(xrow + n) * 104 + c0 + q] = (c0 + q == 80) ? (__bf16)1.0f : (__bf16)0.0f;
    }

    // phase 3b: gates GEMM
    f32x4 acc[12], ani4[4];
#pragma unroll
    for (int i = 0; i < 12; ++i) acc[i] = (f32x4){0.f, 0.f, 0.f, 0.f};
#pragma unroll
    for (int i = 0; i < 4; ++i) ani4[i] = (f32x4){0.f, 0.f, 0.f, 0.f};
    bf16x8 af[3];
#pragma unroll
    for (int kk = 0; kk < 3; ++kk)
        af[kk] = *(const bf16x8*)&s_X[(xrow + c16) * 104 + kk * 32 + lq * 8];
#pragma unroll
    for (int ct = 0; ct < 12; ++ct) {
#pragma unroll
        for (int kk = 0; kk < 3; ++kk) {
            bf16x8 bf = *(const bf16x8*)&s_W[(ct * 3 + kk) * 512 + lane * 8];
            acc[ct] = __builtin_amdgcn_mfma_f32_16x16x32_bf16(af[kk], bf, acc[ct], 0, 0, 0);
        }
    }
#pragma unroll
    for (int ct8 = 0; ct8 < 4; ++ct8) {
        bf16x8 bf = *(const bf16x8*)&s_W[(36 + ct8) * 512 + lane * 8];
        ani4[ct8] = __builtin_amdgcn_mfma_f32_16x16x32_bf16(af[0], bf, ani4[ct8], 0, 0, 0);
    }

    // GRU epilogue (hold from s_X bf16); keep h_new in registers
    float hn[4][4];
#pragma unroll
    for (int ct = 0; ct < 4; ++ct) {
        float bni = bih[128 + ct * 16 + c16];
#pragma unroll
        for (int jr = 0; jr < 4; ++jr) {
            float hold = (float)s_X[(xrow + 4 * lq + jr) * 104 + 16 + ct * 16 + c16];
            float rr = 1.f / (1.f + __expf(-acc[ct][jr]));
            float zz = 1.f / (1.f + __expf(-acc[4 + ct][jr]));
            float xx = fmaf(rr, acc[8 + ct][jr], ani4[ct][jr] + bni);
            float ax = fabsf(xx);
            float ee = __expf(-2.f * ax);
            float ncv = __builtin_copysignf((1.f - ee) / (1.f + ee), xx);
            hn[ct][jr] = fmaf(zz, hold - ncv, ncv);
        }
    }
    // write h_new into s_X (same-wave DS order), then coalesced bf16 writeback to h
#pragma unroll
    for (int ct = 0; ct < 4; ++ct)
#pragma unroll
        for (int jr = 0; jr < 4; ++jr)
            s_X[(xrow + 4 * lq + jr) * 104 + 16 + ct * 16 + c16] = (__bf16)hn[ct][jr];
    {
        bf16x8* hdst = (bf16x8*)(h + (size_t)nwb * 64);
#pragma unroll
        for (int ii = 0; ii < 2; ++ii) {
            int idx = lane + 64 * ii;
            int n = idx >> 3, d8 = idx & 7;
            bf16x8 v = *(const bf16x8*)&s_X[(xrow + n) * 104 + 16 + d8 * 8];
            hdst[idx] = v;
        }
    }

    if (!do_final) {
        // fused lin1 -> out1_out (bf16)
        f32x4 o1acc = (f32x4){0.f, 0.f, 0.f, 0.f};
#pragma unroll
        for (int kk = 0; kk < 2; ++kk) {
            bf16x8 a = *(const bf16x8*)&s_X[(xrow + c16) * 104 + 16 + kk * 32 + lq * 8];
            bf16x8 b = *(const bf16x8*)&s_w1[kk * 512 + lane * 8];
            o1acc = __builtin_amdgcn_mfma_f32_16x16x32_bf16(a, b, o1acc, 0, 0, 0);
        }
        float lb = lin1_b[c16];
#pragma unroll
        for (int jr = 0; jr < 4; ++jr) {
            int node = nwb + 4 * lq + jr;
            out1_out[(size_t)node * 16 + c16] = (__bf16)(o1acc[jr] + lb);
        }
    } else {
        // fused final: y = h_new @ lin2_w ; atomicAdd into out[batch]
        float w2v[4];
#pragma unroll
        for (int ct = 0; ct < 4; ++ct) w2v[ct] = lin2_w[ct * 16 + c16];
#pragma unroll
        for (int jr = 0; jr < 4; ++jr) {
            float part = hn[0][jr] * w2v[0];
            part = fmaf(hn[1][jr], w2v[1], part);
            part = fmaf(hn[2][jr], w2v[2], part);
            part = fmaf(hn[3][jr], w2v[3], part);
#pragma unroll
            for (int off = 8; off > 0; off >>= 1) part += __shfl_xor(part, off, 64);
            if (c16 == 0) {
                int node = nwb + 4 * lq + jr;
                atomicAdd(&out[batch[node]], part);
            }
        }
    }
}

extern "C" void kernel_launch(void* const* d_in, const int* in_sizes, int n_in,
                              void* d_out, int out_size, void* d_ws, size_t ws_size,
                              hipStream_t stream) {
    const float* x        = (const float*)d_in[0];
    const float* edge_attr= (const float*)d_in[1];
    const float* lin0_w   = (const float*)d_in[2];
    const float* lin0_b   = (const float*)d_in[3];
    const float* nn1_w    = (const float*)d_in[4];
    const float* nn1_b    = (const float*)d_in[5];
    const float* root_w   = (const float*)d_in[6];
    const float* conv_b   = (const float*)d_in[7];
    const float* gru_w_ih = (const float*)d_in[8];
    const float* gru_w_hh = (const float*)d_in[9];
    const float* gru_b_ih = (const float*)d_in[10];
    const float* gru_b_hh = (const float*)d_in[11];
    const float* lin1_w   = (const float*)d_in[12];
    const float* lin1_b   = (const float*)d_in[13];
    const float* lin2_w   = (const float*)d_in[14];
    const int*   ei       = (const int*)d_in[15];
    const int*   batch    = (const int*)d_in[16];
    float* out = (float*)d_out;

    char* p = (char*)d_ws;
    __bf16* h       = (__bf16*)p;           p += (size_t)N_NODES * DIM * 2;
    __bf16* out1A   = (__bf16*)p;           p += (size_t)N_NODES * DNN * 2;
    __bf16* out1B   = (__bf16*)p;           p += (size_t)N_NODES * DNN * 2;
    float4* csr_ea  = (float4*)p;           p += (size_t)N_EDGES * 16;
    __bf16* Wb      = (__bf16*)p;           p += (size_t)WB_SZ * 2;
    __bf16* B2b     = (__bf16*)p;           p += 1536 * 2;
    __bf16* w1b     = (__bf16*)p;           p += 1024 * 2;
    int*    cnt     = (int*)p;              p += (size_t)N_NODES * 4;
    float*  inv_cnt = (float*)p;            p += (size_t)N_NODES * 4;
    int*    row_ptr = (int*)p;              p += (size_t)(N_NODES + 16) * 4;
    int*    cursor  = (int*)p;              p += (size_t)N_NODES * 4;
    int*    excl    = (int*)p;              p += (size_t)N_NODES * 4;
    int*    bsum    = (int*)p;              p += 512 * 4;
    int*    boff    = (int*)p;              p += 512 * 4;
    int*    csr_src = (int*)p;              p += (size_t)N_EDGES * 4;

    hipMemsetAsync(d_out, 0, (size_t)NG * 4, stream);
    hipMemsetAsync(cnt, 0, (size_t)N_NODES * 4, stream);
    k_prep<<<330, 256, 0, stream>>>(gru_w_ih, gru_w_hh, root_w, lin1_w, gru_b_ih, gru_b_hh,
                                    nn1_w, nn1_b, Wb, B2b, w1b);
    k_degree<<<N_EDGES / 256, 256, 0, stream>>>(ei, cnt);
    k_scanA<<<N_NODES / 256, 256, 0, stream>>>(cnt, excl, bsum);
    k_scanB<<<1, 256, 0, stream>>>(bsum, boff);
    k_scanC<<<N_NODES / 256, 256, 0, stream>>>(excl, boff, row_ptr, cursor);
    k_scatter<<<N_EDGES / 256, 256, 0, stream>>>(ei, edge_attr, cursor, csr_src, csr_ea);
    k_invcnt<<<N_NODES / 256, 256, 0, stream>>>(cnt, inv_cnt);
    k_init<<<N_NODES / 16, 256, 0, stream>>>(x, lin0_w, lin0_b, h);
    k_lin1<<<N_NODES / 64, 256, 0, stream>>>(h, lin1_w, lin1_b, out1A);

    for (int it = 0; it < N_ITERS; ++it) {
        int j = it >> 1;   // GRU index (NL2 = 2)
        const __bf16* o_in = (it & 1) ? out1B : out1A;
        __bf16*       o_out= (it & 1) ? out1A : out1B;
        k_node<<<N_NODES / 128, 512, 0, stream>>>(o_in, o_out, csr_src, csr_ea, row_ptr, inv_cnt,
                                                  h, Wb + (size_t)j * 40 * 512, B2b, w1b,
                                                  conv_b, gru_b_ih + (size_t)j * 192, lin1_b,
                                                  batch, lin2_w, out, it == N_ITERS - 1 ? 1 : 0);
    }
}

// Round 18
// 400.302 us; speedup vs baseline: 5.4500x; 1.0195x over previous
//
#include <hip/hip_runtime.h>
#include <hip/hip_bf16.h>

#define N_NODES 131072
#define N_EDGES 524288
#define F_IN 16
#define DIM 64
#define DNN 16
#define BK 4
#define NG 8192
#define N_ITERS 8   // NL1*NL2

typedef __bf16 bf16x8 __attribute__((ext_vector_type(8)));
typedef __bf16 bf16x4 __attribute__((ext_vector_type(4)));
typedef float f32x4 __attribute__((ext_vector_type(4)));

#define FMA4(A_, S_, W_) { (A_).x = fmaf((S_), (W_).x, (A_).x); (A_).y = fmaf((S_), (W_).y, (A_).y); \
                           (A_).z = fmaf((S_), (W_).z, (A_).z); (A_).w = fmaf((S_), (W_).w, (A_).w); }

// ---------------- degree (int) ----------------
__global__ __launch_bounds__(256) void k_degree(const int* __restrict__ ei, int* __restrict__ cnt) {
    int e = blockIdx.x * 256 + threadIdx.x;
    atomicAdd(&cnt[ei[N_EDGES + e]], 1);
}

__global__ __launch_bounds__(256) void k_invcnt(const int* __restrict__ cnt, float* __restrict__ inv) {
    int i = blockIdx.x * 256 + threadIdx.x;
    inv[i] = 1.0f / (float)max(cnt[i], 1);
}

// ---------------- CSR scan ----------------
__global__ __launch_bounds__(256) void k_scanA(const int* __restrict__ cnt, int* __restrict__ excl,
                                               int* __restrict__ bsum) {
    __shared__ int a[256], b[256];
    int t = threadIdx.x, gid = blockIdx.x * 256 + t;
    int c = cnt[gid];
    a[t] = c; __syncthreads();
    int *s = a, *d = b;
#pragma unroll
    for (int off = 1; off < 256; off <<= 1) {
        d[t] = s[t] + (t >= off ? s[t - off] : 0);
        __syncthreads();
        int* tmp = s; s = d; d = tmp;
    }
    excl[gid] = s[t] - c;
    if (t == 255) bsum[blockIdx.x] = s[255];
}

__global__ __launch_bounds__(256) void k_scanB(const int* __restrict__ bsum, int* __restrict__ boff) {
    __shared__ int a[512], b[512];
    int t = threadIdx.x;
    a[t] = bsum[t]; a[t + 256] = bsum[t + 256];
    __syncthreads();
    int *s = a, *d = b;
#pragma unroll
    for (int off = 1; off < 512; off <<= 1) {
        d[t] = s[t] + (t >= off ? s[t - off] : 0);
        int i2 = t + 256;
        d[i2] = s[i2] + (i2 >= off ? s[i2 - off] : 0);
        __syncthreads();
        int* tmp = s; s = d; d = tmp;
    }
    boff[t] = t ? s[t - 1] : 0;
    boff[t + 256] = s[t + 255];
}

__global__ __launch_bounds__(256) void k_scanC(const int* __restrict__ excl, const int* __restrict__ boff,
                                               int* __restrict__ row_ptr, int* __restrict__ cursor) {
    int gid = blockIdx.x * 256 + threadIdx.x;
    int v = excl[gid] + boff[gid >> 8];
    row_ptr[gid] = v;
    cursor[gid] = v;
    if (gid == 0) row_ptr[N_NODES] = N_EDGES;
}

__global__ __launch_bounds__(256) void k_scatter(const int* __restrict__ ei, const float* __restrict__ ea,
                                                 int* __restrict__ cursor, int* __restrict__ csr_src,
                                                 float4* __restrict__ csr_ea) {
    int e = blockIdx.x * 256 + threadIdx.x;
    int dst = ei[N_EDGES + e];
    int pos = atomicAdd(&cursor[dst], 1);
    csr_src[pos] = ei[e];
    csr_ea[pos] = ((const float4*)ea)[e];
}

// ---------------- prep: bf16 B-fragment weight tiles ----------------
#define WB_SZ (4 * 40 * 512)
__global__ __launch_bounds__(256) void k_prep(const float* __restrict__ wih, const float* __restrict__ whh,
                                              const float* __restrict__ rw, const float* __restrict__ w1,
                                              const float* __restrict__ bih, const float* __restrict__ bhh,
                                              const float* __restrict__ nn1w, const float* __restrict__ nn1b,
                                              __bf16* __restrict__ Wb, __bf16* __restrict__ B2b,
                                              __bf16* __restrict__ w1b) {
    int idx = blockIdx.x * 256 + threadIdx.x;
    if (idx < WB_SZ) {
        int j = idx / 20480, r = idx % 20480;
        int t = r >> 9, e = r & 511;
        int jj = e & 7, c16 = (e >> 3) & 15, kq = e >> 7;
        int ct, kk; bool nih = false;
        if (t < 36) { ct = t / 3; kk = t % 3; } else { ct = 8 + (t - 36); kk = 0; nih = true; }
        int k = kk * 32 + kq * 8 + jj;
        int c = ct * 16 + c16;
        bool ngate = ct >= 8;
        float v = 0.f;
        if (nih) {
            if (k < 16) v = wih[((size_t)j * 192 + c) * 16 + k];
        } else {
            if (k < 16) v = ngate ? 0.f : wih[((size_t)j * 192 + c) * 16 + k];
            else if (k < 80) v = whh[((size_t)j * 192 + c) * 64 + (k - 16)];
            else if (k == 80) v = ngate ? bhh[j * 192 + c] : (bih[j * 192 + c] + bhh[j * 192 + c]);
        }
        Wb[idx] = (__bf16)v;
    } else if (idx < WB_SZ + 1536) {
        int e = idx - WB_SZ;
        int t = e >> 9, ee = e & 511;
        int jj = ee & 7, c16 = (ee >> 3) & 15, kq = ee >> 7;
        int krow = t * 32 + kq * 8 + jj;
        float v;
        if (krow < 16) v = rw[krow * 16 + c16];
        else {
            int i = (krow - 16) >> 4, kk = (krow - 16) & 15;
            v = (i == 0) ? nn1b[kk * 16 + c16] : nn1w[(i - 1) * 256 + kk * 16 + c16];
        }
        B2b[e] = (__bf16)v;
    } else if (idx < WB_SZ + 1536 + 1024) {
        int e = idx - (WB_SZ + 1536);
        int t2 = e >> 9, ee = e & 511;
        int jj = ee & 7, c16 = (ee >> 3) & 15, kq = ee >> 7;
        int k = t2 * 32 + kq * 8 + jj;
        w1b[e] = (__bf16)w1[k * 16 + c16];
    }
}

// ---------------- init: h = relu(x @ lin0_w + lin0_b) -> bf16 ----------------
__global__ __launch_bounds__(256) void k_init(const float* __restrict__ x, const float* __restrict__ w,
                                              const float* __restrict__ b, __bf16* __restrict__ h) {
    __shared__ float s_w[F_IN * DIM];
    int tid = threadIdx.x;
    for (int i = tid; i < F_IN * DIM; i += 256) s_w[i] = w[i];
    int node = blockIdx.x * 16 + (tid >> 4);
    int c4 = tid & 15;
    const float4* xp = (const float4*)(x + (size_t)node * F_IN);
    float4 x0 = xp[0], x1 = xp[1], x2 = xp[2], x3 = xp[3];
    float xa[16] = {x0.x, x0.y, x0.z, x0.w, x1.x, x1.y, x1.z, x1.w,
                    x2.x, x2.y, x2.z, x2.w, x3.x, x3.y, x3.z, x3.w};
    __syncthreads();
    float4 acc = ((const float4*)b)[c4];
    const float4* w4 = (const float4*)s_w;
#pragma unroll
    for (int k = 0; k < 16; ++k) {
        float4 wv = w4[k * 16 + c4];
        FMA4(acc, xa[k], wv);
    }
    bf16x4 hv;
    hv[0] = (__bf16)fmaxf(acc.x, 0.f); hv[1] = (__bf16)fmaxf(acc.y, 0.f);
    hv[2] = (__bf16)fmaxf(acc.z, 0.f); hv[3] = (__bf16)fmaxf(acc.w, 0.f);
    *(bf16x4*)&h[(size_t)node * DIM + c4 * 4] = hv;
}

// ---------------- out1 = h @ lin1_w + lin1_b (once, pre-loop; bf16 in/out) ----------------
__global__ __launch_bounds__(256) void k_lin1(const __bf16* __restrict__ h, const float* __restrict__ w,
                                              const float* __restrict__ b, __bf16* __restrict__ out1) {
    __shared__ float s_h[64 * 68];
    int tid = threadIdx.x;
    int nb = blockIdx.x * 64;
    for (int i = tid; i < 64 * 16; i += 256) {
        int n = i >> 4, q4 = i & 15;
        bf16x4 v = *(const bf16x4*)&h[(size_t)(nb + n) * 64 + q4 * 4];
        float* d = &s_h[n * 68 + q4 * 4];
        d[0] = (float)v[0]; d[1] = (float)v[1]; d[2] = (float)v[2]; d[3] = (float)v[3];
    }
    int ct = tid & 15;
    float wcol[64];
#pragma unroll
    for (int q = 0; q < 64; ++q) wcol[q] = w[q * 16 + ct];
    float bias = b[ct];
    __syncthreads();
    int ng = tid >> 4;
#pragma unroll
    for (int rep = 0; rep < 4; ++rep) {
        int nl = ng + 16 * rep;
        float acc = bias;
#pragma unroll
        for (int q4 = 0; q4 < 16; ++q4) {
            float4 hv = *(const float4*)&s_h[nl * 68 + q4 * 4];
            acc = fmaf(hv.x, wcol[4 * q4 + 0], acc);
            acc = fmaf(hv.y, wcol[4 * q4 + 1], acc);
            acc = fmaf(hv.z, wcol[4 * q4 + 2], acc);
            acc = fmaf(hv.w, wcol[4 * q4 + 3], acc);
        }
        out1[(size_t)(nb + nl) * 16 + ct] = (__bf16)acc;
    }
}

// ---------------- node v12: wave-private gather (single barrier) + MFMA GRU ----------------
// vs v11: gather remapped so wave w gathers its OWN 16 s_X rows (group gi=lane>>4
// handles nodes nwb+gi*4+r). All gather->MFMA->epilogue ordering is same-wave DS
// program order -> the only __syncthreads is after cooperative weight staging.
// Waves no longer wait for the block's worst-degree group (was ~13 rounds max);
// each wave stalls only on its own ~max-of-16 (~10) and desyncs vs other waves.
// Gather loop: fixed trip count (max deg of 4 chains), masked accumulate.
__attribute__((amdgpu_waves_per_eu(2, 4)))
__global__ __launch_bounds__(512) void k_node(
    const __bf16* __restrict__ out1_in, __bf16* __restrict__ out1_out,
    const int* __restrict__ csr_src, const float4* __restrict__ csr_ea,
    const int* __restrict__ row_ptr, const float* __restrict__ inv_cnt,
    __bf16* __restrict__ h, const __bf16* __restrict__ Wb, const __bf16* __restrict__ B2b,
    const __bf16* __restrict__ w1b, const float* __restrict__ conv_b,
    const float* __restrict__ bih, const float* __restrict__ lin1_b,
    const int* __restrict__ batch, const float* __restrict__ lin2_w,
    float* __restrict__ out, int do_final)
{
    __shared__ __align__(16) __bf16 s_X[128 * 104];  // 26624 B
    __shared__ __align__(16) __bf16 s_W[40 * 512];   // 40960 B
    __shared__ __align__(16) __bf16 s_B2[3 * 512];   //  3072 B
    __shared__ __align__(16) __bf16 s_w1[1024];      //  2048 B  (total 72704)
    int tid = threadIdx.x;
    int nb = blockIdx.x * 128;
    int lane = tid & 63, w = tid >> 6;               // w = 0..7
    int c16 = lane & 15, lq = lane >> 4;
    int nwb = nb + w * 16;
    int xrow = w * 16;

    // cooperative staging of weight tiles (512 threads)
    {
        const float4* src = (const float4*)Wb;
        float4* dst = (float4*)s_W;
#pragma unroll
        for (int i = 0; i < 5; ++i) dst[tid + 512 * i] = src[tid + 512 * i];
        if (tid < 192) ((float4*)s_B2)[tid] = ((const float4*)B2b)[tid];
        else if (tid < 320) ((float4*)s_w1)[tid - 192] = ((const float4*)w1b)[tid - 192];
    }
    // own out1 row -> X2[.][0..15]  (wave-private rows)
    {
        int n = lane >> 2, k4 = lane & 3;
        bf16x4 v = *(const bf16x4*)&out1_in[(size_t)(nwb + n) * 16 + k4 * 4];
        *(bf16x4*)&s_X[(xrow + n) * 104 + k4 * 4] = v;
    }
    // pad cols 80..103 = {1,0,...} (wave-private rows)
    {
        int n = lane >> 2, c0 = 80 + (lane & 3) * 6;
#pragma unroll
        for (int q = 0; q < 6; ++q) {
            int col = c0 + q;
            s_X[(xrow + n) * 104 + col] = (col == 80) ? (__bf16)1.0f : (__bf16)0.0f;
        }
    }
    __syncthreads();   // the ONLY block-wide barrier (covers s_W/s_B2/s_w1)

    // gather: wave-private. group gi = lane>>4 handles nodes nwb + gi*4 + r (r=0..3)
    {
        int gi = lane >> 4, k = lane & 15;
        int e0[4], dr[4], vs[4];
        float S0[4] = {0.f,0.f,0.f,0.f}, S1[4] = {0.f,0.f,0.f,0.f}, S2[4] = {0.f,0.f,0.f,0.f},
              S3[4] = {0.f,0.f,0.f,0.f}, S4[4] = {0.f,0.f,0.f,0.f};
        int rounds = 0;
#pragma unroll
        for (int r = 0; r < 4; ++r) {
            int n = nwb + gi * 4 + r;
            e0[r] = row_ptr[n];
            dr[r] = row_ptr[n + 1] - e0[r];
            rounds = max(rounds, dr[r]);
            vs[r] = csr_src[min(e0[r], N_EDGES - 1)];
        }
        for (int t = 0; t < rounds; ++t) {
            float4 av[4]; float xv[4]; int vs2[4];
#pragma unroll
            for (int r = 0; r < 4; ++r) {
                int e = min(e0[r] + t, N_EDGES - 1);
                av[r] = csr_ea[e];
                vs2[r] = csr_src[min(e + 1, N_EDGES - 1)];
            }
#pragma unroll
            for (int r = 0; r < 4; ++r)
                xv[r] = (float)out1_in[(size_t)(vs[r] & 0xFFFFF) * 16 + k];
#pragma unroll
            for (int r = 0; r < 4; ++r) {
                float xm = (t < dr[r]) ? xv[r] : 0.0f;
                S0[r] += xm;
                S1[r] = fmaf(av[r].x, xm, S1[r]);
                S2[r] = fmaf(av[r].y, xm, S2[r]);
                S3[r] = fmaf(av[r].z, xm, S3[r]);
                S4[r] = fmaf(av[r].w, xm, S4[r]);
                vs[r] = vs2[r];
            }
        }
#pragma unroll
        for (int r = 0; r < 4; ++r) {
            int nl = xrow + gi * 4 + r;
            float inv = inv_cnt[nwb + gi * 4 + r];
            __bf16* p = &s_X[nl * 104];
            p[16 + k] = (__bf16)(S0[r] * inv);
            p[32 + k] = (__bf16)(S1[r] * inv);
            p[48 + k] = (__bf16)(S2[r] * inv);
            p[64 + k] = (__bf16)(S3[r] * inv);
            p[80 + k] = (__bf16)(S4[r] * inv);
        }
    }
    // no barrier: s_X rows are wave-private; same-wave DS ops are in program order

    // phase 2: o2 = X2 @ B2 + conv_b (K=96)
    float cb = conv_b[c16];
    f32x4 co2 = (f32x4){cb, cb, cb, cb};
#pragma unroll
    for (int kk = 0; kk < 3; ++kk) {
        bf16x8 a = *(const bf16x8*)&s_X[(xrow + c16) * 104 + kk * 32 + lq * 8];
        bf16x8 b = *(const bf16x8*)&s_B2[kk * 512 + lane * 8];
        co2 = __builtin_amdgcn_mfma_f32_16x16x32_bf16(a, b, co2, 0, 0, 0);
    }

    // phase 3a: rebuild X = [o2(16) | h(64) | 1 | 0..]  (wave-own rows)
#pragma unroll
    for (int jr = 0; jr < 4; ++jr)
        s_X[(xrow + 4 * lq + jr) * 104 + c16] = (__bf16)co2[jr];
    {
        const bf16x8* hsrc = (const bf16x8*)(h + (size_t)nwb * 64);
#pragma unroll
        for (int ii = 0; ii < 2; ++ii) {
            int idx = lane + 64 * ii;
            int n = idx >> 3, d8 = idx & 7;
            bf16x8 v = hsrc[idx];
            *(bf16x8*)&s_X[(xrow + n) * 104 + 16 + d8 * 8] = v;
        }
    }
    {
        int n = lane >> 2, c0 = 80 + (lane & 3) * 4;
#pragma unroll
        for (int q = 0; q < 4; ++q)
            s_X[(xrow + n) * 104 + c0 + q] = (c0 + q == 80) ? (__bf16)1.0f : (__bf16)0.0f;
    }

    // phase 3b: gates GEMM
    f32x4 acc[12], ani4[4];
#pragma unroll
    for (int i = 0; i < 12; ++i) acc[i] = (f32x4){0.f, 0.f, 0.f, 0.f};
#pragma unroll
    for (int i = 0; i < 4; ++i) ani4[i] = (f32x4){0.f, 0.f, 0.f, 0.f};
    bf16x8 af[3];
#pragma unroll
    for (int kk = 0; kk < 3; ++kk)
        af[kk] = *(const bf16x8*)&s_X[(xrow + c16) * 104 + kk * 32 + lq * 8];
#pragma unroll
    for (int ct = 0; ct < 12; ++ct) {
#pragma unroll
        for (int kk = 0; kk < 3; ++kk) {
            bf16x8 bf = *(const bf16x8*)&s_W[(ct * 3 + kk) * 512 + lane * 8];
            acc[ct] = __builtin_amdgcn_mfma_f32_16x16x32_bf16(af[kk], bf, acc[ct], 0, 0, 0);
        }
    }
#pragma unroll
    for (int ct8 = 0; ct8 < 4; ++ct8) {
        bf16x8 bf = *(const bf16x8*)&s_W[(36 + ct8) * 512 + lane * 8];
        ani4[ct8] = __builtin_amdgcn_mfma_f32_16x16x32_bf16(af[0], bf, ani4[ct8], 0, 0, 0);
    }

    // GRU epilogue (hold from s_X bf16); keep h_new in registers
    float hn[4][4];
#pragma unroll
    for (int ct = 0; ct < 4; ++ct) {
        float bni = bih[128 + ct * 16 + c16];
#pragma unroll
        for (int jr = 0; jr < 4; ++jr) {
            float hold = (float)s_X[(xrow + 4 * lq + jr) * 104 + 16 + ct * 16 + c16];
            float rr = 1.f / (1.f + __expf(-acc[ct][jr]));
            float zz = 1.f / (1.f + __expf(-acc[4 + ct][jr]));
            float xx = fmaf(rr, acc[8 + ct][jr], ani4[ct][jr] + bni);
            float ax = fabsf(xx);
            float ee = __expf(-2.f * ax);
            float ncv = __builtin_copysignf((1.f - ee) / (1.f + ee), xx);
            hn[ct][jr] = fmaf(zz, hold - ncv, ncv);
        }
    }
    // write h_new into s_X (same-wave DS order), then coalesced bf16 writeback to h
#pragma unroll
    for (int ct = 0; ct < 4; ++ct)
#pragma unroll
        for (int jr = 0; jr < 4; ++jr)
            s_X[(xrow + 4 * lq + jr) * 104 + 16 + ct * 16 + c16] = (__bf16)hn[ct][jr];
    {
        bf16x8* hdst = (bf16x8*)(h + (size_t)nwb * 64);
#pragma unroll
        for (int ii = 0; ii < 2; ++ii) {
            int idx = lane + 64 * ii;
            int n = idx >> 3, d8 = idx & 7;
            bf16x8 v = *(const bf16x8*)&s_X[(xrow + n) * 104 + 16 + d8 * 8];
            hdst[idx] = v;
        }
    }

    if (!do_final) {
        // fused lin1 -> out1_out (bf16)
        f32x4 o1acc = (f32x4){0.f, 0.f, 0.f, 0.f};
#pragma unroll
        for (int kk = 0; kk < 2; ++kk) {
            bf16x8 a = *(const bf16x8*)&s_X[(xrow + c16) * 104 + 16 + kk * 32 + lq * 8];
            bf16x8 b = *(const bf16x8*)&s_w1[kk * 512 + lane * 8];
            o1acc = __builtin_amdgcn_mfma_f32_16x16x32_bf16(a, b, o1acc, 0, 0, 0);
        }
        float lb = lin1_b[c16];
#pragma unroll
        for (int jr = 0; jr < 4; ++jr) {
            int node = nwb + 4 * lq + jr;
            out1_out[(size_t)node * 16 + c16] = (__bf16)(o1acc[jr] + lb);
        }
    } else {
        // fused final: y = h_new @ lin2_w ; atomicAdd into out[batch]
        float w2v[4];
#pragma unroll
        for (int ct = 0; ct < 4; ++ct) w2v[ct] = lin2_w[ct * 16 + c16];
#pragma unroll
        for (int jr = 0; jr < 4; ++jr) {
            float part = hn[0][jr] * w2v[0];
            part = fmaf(hn[1][jr], w2v[1], part);
            part = fmaf(hn[2][jr], w2v[2], part);
            part = fmaf(hn[3][jr], w2v[3], part);
#pragma unroll
            for (int off = 8; off > 0; off >>= 1) part += __shfl_xor(part, off, 64);
            if (c16 == 0) {
                int node = nwb + 4 * lq + jr;
                atomicAdd(&out[batch[node]], part);
            }
        }
    }
}

extern "C" void kernel_launch(void* const* d_in, const int* in_sizes, int n_in,
                              void* d_out, int out_size, void* d_ws, size_t ws_size,
                              hipStream_t stream) {
    const float* x        = (const float*)d_in[0];
    const float* edge_attr= (const float*)d_in[1];
    const float* lin0_w   = (const float*)d_in[2];
    const float* lin0_b   = (const float*)d_in[3];
    const float* nn1_w    = (const float*)d_in[4];
    const float* nn1_b    = (const float*)d_in[5];
    const float* root_w   = (const float*)d_in[6];
    const float* conv_b   = (const float*)d_in[7];
    const float* gru_w_ih = (const float*)d_in[8];
    const float* gru_w_hh = (const float*)d_in[9];
    const float* gru_b_ih = (const float*)d_in[10];
    const float* gru_b_hh = (const float*)d_in[11];
    const float* lin1_w   = (const float*)d_in[12];
    const float* lin1_b   = (const float*)d_in[13];
    const float* lin2_w   = (const float*)d_in[14];
    const int*   ei       = (const int*)d_in[15];
    const int*   batch    = (const int*)d_in[16];
    float* out = (float*)d_out;

    char* p = (char*)d_ws;
    __bf16* h       = (__bf16*)p;           p += (size_t)N_NODES * DIM * 2;
    __bf16* out1A   = (__bf16*)p;           p += (size_t)N_NODES * DNN * 2;
    __bf16* out1B   = (__bf16*)p;           p += (size_t)N_NODES * DNN * 2;
    float4* csr_ea  = (float4*)p;           p += (size_t)N_EDGES * 16;
    __bf16* Wb      = (__bf16*)p;           p += (size_t)WB_SZ * 2;
    __bf16* B2b     = (__bf16*)p;           p += 1536 * 2;
    __bf16* w1b     = (__bf16*)p;           p += 1024 * 2;
    int*    cnt     = (int*)p;              p += (size_t)N_NODES * 4;
    float*  inv_cnt = (float*)p;            p += (size_t)N_NODES * 4;
    int*    row_ptr = (int*)p;              p += (size_t)(N_NODES + 16) * 4;
    int*    cursor  = (int*)p;              p += (size_t)N_NODES * 4;
    int*    excl    = (int*)p;              p += (size_t)N_NODES * 4;
    int*    bsum    = (int*)p;              p += 512 * 4;
    int*    boff    = (int*)p;              p += 512 * 4;
    int*    csr_src = (int*)p;              p += (size_t)N_EDGES * 4;

    hipMemsetAsync(d_out, 0, (size_t)NG * 4, stream);
    hipMemsetAsync(cnt, 0, (size_t)N_NODES * 4, stream);
    k_prep<<<330, 256, 0, stream>>>(gru_w_ih, gru_w_hh, root_w, lin1_w, gru_b_ih, gru_b_hh,
                                    nn1_w, nn1_b, Wb, B2b, w1b);
    k_degree<<<N_EDGES / 256, 256, 0, stream>>>(ei, cnt);
    k_scanA<<<N_NODES / 256, 256, 0, stream>>>(cnt, excl, bsum);
    k_scanB<<<1, 256, 0, stream>>>(bsum, boff);
    k_scanC<<<N_NODES / 256, 256, 0, stream>>>(excl, boff, row_ptr, cursor);
    k_scatter<<<N_EDGES / 256, 256, 0, stream>>>(ei, edge_attr, cursor, csr_src, csr_ea);
    k_invcnt<<<N_NODES / 256, 256, 0, stream>>>(cnt, inv_cnt);
    k_init<<<N_NODES / 16, 256, 0, stream>>>(x, lin0_w, lin0_b, h);
    k_lin1<<<N_NODES / 64, 256, 0, stream>>>(h, lin1_w, lin1_b, out1A);

    for (int it = 0; it < N_ITERS; ++it) {
        int j = it >> 1;   // GRU index (NL2 = 2)
        const __bf16* o_in = (it & 1) ? out1B : out1A;
        __bf16*       o_out= (it & 1) ? out1A : out1B;
        k_node<<<N_NODES / 128, 512, 0, stream>>>(o_in, o_out, csr_src, csr_ea, row_ptr, inv_cnt,
                                                  h, Wb + (size_t)j * 40 * 512, B2b, w1b,
                                                  conv_b, gru_b_ih + (size_t)j * 192, lin1_b,
                                                  batch, lin2_w, out, it == N_ITERS - 1 ? 1 : 0);
    }
}